// Round 15
// baseline (207.381 us; speedup 1.0000x reference)
//
#include <hip/hip_runtime.h>
#include <hip/hip_bf16.h>
#include <math.h>

using short8 = __attribute__((ext_vector_type(8))) short;   // 8 bf16 (4 VGPR)
using f32x4  = __attribute__((ext_vector_type(4))) float;   // MFMA acc
typedef unsigned long long u64;

#define MFMA16(a, b, c) __builtin_amdgcn_mfma_f32_16x16x32_bf16(a, b, c, 0, 0, 0)

__device__ __forceinline__ short f2bs(float f) {
    __hip_bfloat16 h = __float2bfloat16(f);          // RNE
    return __builtin_bit_cast(short, h);
}
__device__ __forceinline__ float bs2f(short s) {
    return __uint_as_float(((unsigned)(unsigned short)s) << 16);
}

// ---------------- mega-prep: all weight conversions + transposes in ONE launch ----------------
__global__ void __launch_bounds__(256) k_megaprep(
        const float* __restrict__ w1, const float* __restrict__ w2,
        const float* __restrict__ w3, const float* __restrict__ fcW,
        const float* __restrict__ Wih, const float* __restrict__ Whh,
        const float* __restrict__ A1, const float* __restrict__ C1,
        const float* __restrict__ A2, const float* __restrict__ C2,
        const float* __restrict__ h0, const int* __restrict__ done,
        const float* __restrict__ bih, const float* __restrict__ bhh,
        const float* __restrict__ Ab1, const float* __restrict__ Cb1,
        short* __restrict__ wc1, short* __restrict__ wc2, short* __restrict__ wc3,
        short* __restrict__ fcwr, short* __restrict__ wihb, short* __restrict__ whhb,
        short* __restrict__ a1b, short* __restrict__ c1b, short* __restrict__ a2b,
        short* __restrict__ c2b, short* __restrict__ hm0,
        float* __restrict__ bias2, float* __restrict__ biasAC, unsigned* __restrict__ flags) {
    __shared__ short t[176 * 76];
    const int bid = blockIdx.x, tid = threadIdx.x;

    auto cvt4 = [&](const float* in, short* out, int i) {
        float4 v = *(const float4*)(in + i * 4);
        out[i * 4 + 0] = f2bs(v.x); out[i * 4 + 1] = f2bs(v.y);
        out[i * 4 + 2] = f2bs(v.z); out[i * 4 + 3] = f2bs(v.w);
    };

    if (bid < 512) {
        // fcW [512][11264] (K = oc*176+pix) -> fcwr [512][pix*64+oc]
        int r = bid;
        for (int it = 0; it < 11; ++it) {
            int c4 = it * 256 + tid;
            float4 v = *(const float4*)(fcW + (size_t)r * 11264 + c4 * 4);
            int c = c4 * 4;
            int oc = c / 176, pix = c % 176;
            t[(pix + 0) * 76 + oc] = f2bs(v.x);
            t[(pix + 1) * 76 + oc] = f2bs(v.y);
            t[(pix + 2) * 76 + oc] = f2bs(v.z);
            t[(pix + 3) * 76 + oc] = f2bs(v.w);
        }
        __syncthreads();
        for (int it = 0; it < 6; ++it) {
            int j8 = it * 256 + tid;
            if (j8 < 1408) {
                int j = j8 * 8, pix = j >> 6, oc0 = j & 63;
                const short* tp = &t[pix * 76 + oc0];
                short8 v;
                ((uint2*)&v)[0] = *(const uint2*)tp;
                ((uint2*)&v)[1] = *(const uint2*)(tp + 4);
                *(short8*)&fcwr[(size_t)r * 11264 + j] = v;
            }
        }
    } else if (bid < 1536) {
        cvt4(Wih, wihb, (bid - 512) * 256 + tid);
    } else if (bid < 2560) {
        cvt4(Whh, whhb, (bid - 1536) * 256 + tid);
    } else if (bid < 2816) {
        cvt4(A1, a1b, (bid - 2560) * 256 + tid);
    } else if (bid < 3072) {
        cvt4(C1, c1b, (bid - 2816) * 256 + tid);
    } else if (bid < 3078) {
        cvt4(w1, wc1, (bid - 3072) * 256 + tid);       // layout already (ic*64+kh*8+kw)
    } else if (bid < 3206) {
        int i = (bid - 3078) * 256 + tid;              // 32768
        int oc = i >> 9, col = i & 511;
        int kh = col >> 7, kw = (col >> 5) & 3, ic = col & 31;
        wc2[i] = f2bs(w2[((oc * 32 + ic) * 4 + kh) * 4 + kw]);
    } else if (bid < 3350) {
        int i = (bid - 3206) * 256 + tid;              // 36864
        int oc = i / 576, col = i % 576;
        int kh = col / 192, r = col % 192, kw = r >> 6, ic = r & 63;
        wc3[i] = f2bs(w3[((oc * 64 + ic) * 3 + kh) * 3 + kw]);
    } else if (bid < 3354) {
        cvt4(A2, a2b, (bid - 3350) * 256 + tid);
    } else if (bid < 3355) {
        if (tid < 128) cvt4(C2, c2b, tid);
    } else if (bid < 3419) {
        int i = (bid - 3355) * 256 + tid;              // 16384
        float m = 1.f - (float)done[i >> 9];
        hm0[i] = f2bs(h0[i] * m);
    } else if (bid < 3427) {
        int i = (bid - 3419) * 256 + tid;              // 2048
        bias2[i] = bih[i] + bhh[i];
    } else if (bid < 3431) {
        int i = (bid - 3427) * 256 + tid;              // 1024
        biasAC[i] = (i < 512) ? Ab1[i] : Cb1[i - 512];
    } else {
        if (tid < 16) flags[tid] = 0u;
    }
}

// ---------------- fused conv1+conv2+conv3 with 16-row conv1 ring buffer ----------------
// ring (40 KB) + img2 (29 KB) + ct (4 KB) = 72.3 KB LDS -> 2 blocks/CU.
// Phases: P1 conv1 rows 0-15 -> P2 conv2 rows 0-6 -> P3 conv1 rows 16-28 (ring slots
// row&15) -> P4 conv2 rows 7-12 -> P5 conv3. 256 threads (keeps 132-VGPR conv1 pipeline).
__global__ void __launch_bounds__(256) k_conv123(
        const float* __restrict__ x,   const short* __restrict__ Wc1,
        const float* __restrict__ b1,
        const short* __restrict__ Wc2, const float* __restrict__ b2,
        const short* __restrict__ Wc3, const float* __restrict__ b3,
        short* __restrict__ y3) {
    __shared__ short ring[19968];       // 16 rows x [39 px][32 oc], swizzled
    __shared__ short img2[14976];       // [13][18][64] swizzled
    __shared__ short ct[2048];          // conv1: [4 waves][16px][32oc]; conv2/3: [2 pairs][16px][64oc]
    const int n = blockIdx.x, tid = threadIdx.x;
    const int w = tid >> 6, l = tid & 63, lr = l & 15, lg = l >> 4;
    const int par = w >> 1, nfh = w & 1;

    // conv1 weights/bias (live across P1 and P3)
    short8 bf1[6][2];
#pragma unroll
    for (int ks = 0; ks < 6; ++ks)
#pragma unroll
        for (int nf = 0; nf < 2; ++nf)
            bf1[ks][nf] = *(const short8*)&Wc1[(nf * 16 + lr) * 192 + ks * 32 + lg * 8];
    const float bc10 = b1[lr], bc11 = b1[16 + lr];
    const float* xb = x + (size_t)n * 57600;

    auto conv1_tiles = [&](int tstart, int tcount) {
        auto tileBase = [&](int tt) -> const float* {
            int p = tt * 16 + lr; if (p > 1130) p = 1130;
            int oh = p / 39, ow = p - oh * 39;
            return xb + (oh * 4) * 160 + ow * 4;
        };
        const int nt = (tcount - w + 3) >> 2;            // tiles tt = tstart + w + 4i
        if (nt <= 0) return;
        float4 fA[6][2], fB[6][2];
        {
            const float* base = tileBase(tstart + w);
#pragma unroll
            for (int ks = 0; ks < 6; ++ks) {
                int ic = ks >> 1, kh = (ks & 1) * 4 + lg;
                const float* ap = base + ic * 19200 + kh * 160;
                fA[ks][0] = *(const float4*)ap;
                fA[ks][1] = *(const float4*)(ap + 4);
            }
        }
        for (int i = 0; i < nt; ++i) {
            const int tt = tstart + w + i * 4;
            if (i + 1 < nt) {                            // prefetch next tile
                const float* nb = tileBase(tt + 4);
#pragma unroll
                for (int ks = 0; ks < 6; ++ks) {
                    int ic = ks >> 1, kh = (ks & 1) * 4 + lg;
                    const float* ap = nb + ic * 19200 + kh * 160;
                    fB[ks][0] = *(const float4*)ap;
                    fB[ks][1] = *(const float4*)(ap + 4);
                }
            }
            f32x4 acc[2] = {};
#pragma unroll
            for (int ks = 0; ks < 6; ++ks) {
                short8 a;
                a[0] = f2bs(fA[ks][0].x); a[1] = f2bs(fA[ks][0].y);
                a[2] = f2bs(fA[ks][0].z); a[3] = f2bs(fA[ks][0].w);
                a[4] = f2bs(fA[ks][1].x); a[5] = f2bs(fA[ks][1].y);
                a[6] = f2bs(fA[ks][1].z); a[7] = f2bs(fA[ks][1].w);
                acc[0] = MFMA16(a, bf1[ks][0], acc[0]);
                acc[1] = MFMA16(a, bf1[ks][1], acc[1]);
            }
#pragma unroll
            for (int j = 0; j < 4; ++j) {
                ct[w * 512 + (lg * 4 + j) * 32 + lr] = f2bs(fmaxf(acc[0][j] + bc10, 0.f));
                ct[w * 512 + (lg * 4 + j) * 32 + 16 + lr] = f2bs(fmaxf(acc[1][j] + bc11, 0.f));
            }
            asm volatile("s_waitcnt lgkmcnt(0)" ::: "memory");
            {
                int row = l >> 2, c8 = (l & 3) * 8;
                int pg = tt * 16 + row;
                if (pg < 1131) {
                    short8 v = *(const short8*)&ct[w * 512 + row * 32 + c8];
                    int prow = pg / 39, pcol = pg - prow * 39;
                    int b = ((prow & 15) * 39 + pcol) * 64 + c8 * 2;   // ring byte offset
                    b ^= ((b >> 7) & 7) << 4;
                    *(short8*)((char*)ring + b) = v;
                }
            }
            asm volatile("s_waitcnt lgkmcnt(0)" ::: "memory");
            if (i + 1 < nt) {
#pragma unroll
                for (int ks = 0; ks < 6; ++ks) {
                    fA[ks][0] = fB[ks][0];
                    fA[ks][1] = fB[ks][1];
                }
            }
        }
    };

    auto conv2_tiles = [&](int pxbase, int pxlast) {      // tiles padded to 8 (wave-uniform)
        short8 bfg[16][2];
#pragma unroll
        for (int ks = 0; ks < 16; ++ks)
#pragma unroll
            for (int q2 = 0; q2 < 2; ++q2)
                bfg[ks][q2] = *(const short8*)&Wc2[(nfh * 32 + q2 * 16 + lr) * 512 + ks * 32 + lg * 8];
        float bc[2] = {b2[nfh * 32 + lr], b2[nfh * 32 + 16 + lr]};
        for (int t = par; t < 8; t += 2) {
            int p = pxbase + t * 16 + lr;
            int pc = p < pxlast ? p : pxlast;
            int oh = pc / 18, ow = pc - oh * 18;
            f32x4 acc[2] = {};
#pragma unroll
            for (int ks = 0; ks < 16; ++ks) {
                int kh = ks >> 2, kw = ks & 3;
                int row = oh * 2 + kh;
                int b = ((row & 15) * 39 + ow * 2 + kw) * 64 + lg * 16;
                b ^= ((b >> 7) & 7) << 4;
                short8 a = *(const short8*)((const char*)ring + b);
                acc[0] = MFMA16(a, bfg[ks][0], acc[0]);
                acc[1] = MFMA16(a, bfg[ks][1], acc[1]);
            }
#pragma unroll
            for (int q2 = 0; q2 < 2; ++q2)
#pragma unroll
                for (int j = 0; j < 4; ++j)
                    ct[par * 1024 + (lg * 4 + j) * 64 + nfh * 32 + q2 * 16 + lr] =
                        f2bs(fmaxf(acc[q2][j] + bc[q2], 0.f));
            __syncthreads();
            int li = nfh * 64 + l;
            int row = li >> 3, c8 = (li & 7) * 8;
            short8 v = *(const short8*)&ct[par * 1024 + row * 64 + c8];
            int pg = pxbase + t * 16 + row;
            if (pg <= pxlast) {
                int b = (pg * 64 + c8) * 2;               // byte offset in img2
                b ^= ((b >> 7) & 7) << 4;
                *(short8*)((char*)img2 + b) = v;
            }
            __syncthreads();
        }
    };

    conv1_tiles(0, 39);            // P1: conv1 rows 0..15 (px 0..623)
    __syncthreads();
    conv2_tiles(0, 125);           // P2: conv2 rows 0..6 (px 0..125)
    __syncthreads();
    conv1_tiles(39, 32);           // P3: conv1 rows 16..28 (px 624..1130) -> ring slots 0..12
    __syncthreads();
    conv2_tiles(126, 233);         // P4: conv2 rows 7..12 (px 126..233)
    __syncthreads();

    // ---- P5: conv3 img2 -> a3 (global) ----
    {
        short8 bfg[18][2];
#pragma unroll
        for (int ks = 0; ks < 18; ++ks)
#pragma unroll
            for (int q2 = 0; q2 < 2; ++q2)
                bfg[ks][q2] = *(const short8*)&Wc3[(nfh * 32 + q2 * 16 + lr) * 576 + ks * 32 + lg * 8];
        float bc[2] = {b3[nfh * 32 + lr], b3[nfh * 32 + 16 + lr]};
        for (int t = par; t < 12; t += 2) {
            int p = t * 16 + lr;
            int pc = p < 176 ? p : 175;
            int oh = pc >> 4, ow = pc & 15;
            int base = (oh * 18 + ow) * 128 + lg * 16;
            f32x4 acc[2] = {};
#pragma unroll
            for (int ks = 0; ks < 18; ++ks) {
                int kh = ks / 6, r6 = ks % 6, kw = r6 >> 1, ich = r6 & 1;
                int b = base + (kh * 18 + kw) * 128 + ich * 64;
                b ^= ((b >> 7) & 7) << 4;
                short8 a = *(const short8*)((const char*)img2 + b);
                acc[0] = MFMA16(a, bfg[ks][0], acc[0]);
                acc[1] = MFMA16(a, bfg[ks][1], acc[1]);
            }
#pragma unroll
            for (int q2 = 0; q2 < 2; ++q2)
#pragma unroll
                for (int j = 0; j < 4; ++j)
                    ct[par * 1024 + (lg * 4 + j) * 64 + nfh * 32 + q2 * 16 + lr] =
                        f2bs(fmaxf(acc[q2][j] + bc[q2], 0.f));
            __syncthreads();
            int li = nfh * 64 + l;
            int row = li >> 3, c8 = (li & 7) * 8;
            short8 v = *(const short8*)&ct[par * 1024 + row * 64 + c8];
            int pg = t * 16 + row;
            if (pg < 176)
                *(short8*)&y3[((size_t)n * 176 + pg) * 64 + c8] = v;
            __syncthreads();
        }
    }
}

// ---------------- MFMA GEMM core (BK=64): part[z][M][N] = A @ W^T ----------------
__global__ void k_gemm_mfma(const short* __restrict__ A, const short* __restrict__ W,
                            float* __restrict__ part, int M, int N, int K, int kPerSplit) {
    __shared__ short As[2][64 * 40];
    __shared__ short Ws[2][64 * 40];
    const int tid = threadIdx.x;
    const int m0 = blockIdx.y * 64, n0 = blockIdx.x * 64;
    const int k0s = blockIdx.z * kPerSplit, k0e = k0s + kPerSplit;
    const int w = tid >> 6, l = tid & 63;
    const int wr = w >> 1, wc = w & 1;
    const int sr = tid >> 2, sc = tid & 3;
    const int lr = l & 15, lg = l >> 4;
    f32x4 acc[2][2] = {};
    for (int k0 = k0s; k0 < k0e; k0 += 64) {
        short8 av0 = *(const short8*)(A + (size_t)(m0 + sr) * K + k0 + sc * 8);
        short8 av1 = *(const short8*)(A + (size_t)(m0 + sr) * K + k0 + 32 + sc * 8);
        short8 wv0 = *(const short8*)(W + (size_t)(n0 + sr) * K + k0 + sc * 8);
        short8 wv1 = *(const short8*)(W + (size_t)(n0 + sr) * K + k0 + 32 + sc * 8);
        __syncthreads();
        *(short8*)&As[0][sr * 40 + sc * 8] = av0;
        *(short8*)&As[1][sr * 40 + sc * 8] = av1;
        *(short8*)&Ws[0][sr * 40 + sc * 8] = wv0;
        *(short8*)&Ws[1][sr * 40 + sc * 8] = wv1;
        __syncthreads();
        int cb = lg * 8;
#pragma unroll
        for (int h = 0; h < 2; ++h) {
            short8 a0 = *(const short8*)&As[h][(wr * 32 + lr) * 40 + cb];
            short8 a1 = *(const short8*)&As[h][(wr * 32 + 16 + lr) * 40 + cb];
            short8 b0 = *(const short8*)&Ws[h][(wc * 32 + lr) * 40 + cb];
            short8 b1 = *(const short8*)&Ws[h][(wc * 32 + 16 + lr) * 40 + cb];
            acc[0][0] = MFMA16(a0, b0, acc[0][0]);
            acc[0][1] = MFMA16(a0, b1, acc[0][1]);
            acc[1][0] = MFMA16(a1, b0, acc[1][0]);
            acc[1][1] = MFMA16(a1, b1, acc[1][1]);
        }
    }
    float* pp = part + (size_t)blockIdx.z * M * N;
#pragma unroll
    for (int mi = 0; mi < 2; ++mi)
#pragma unroll
        for (int ni = 0; ni < 2; ++ni)
#pragma unroll
            for (int j = 0; j < 4; ++j) {
                int row = m0 + wr * 32 + mi * 16 + lg * 4 + j;
                int col = n0 + wc * 32 + ni * 16 + lr;
                pp[(size_t)row * N + col] = acc[mi][ni][j];
            }
}

// FC epilogue: sum splits + bias + leaky -> bf16/f32
__global__ void k_epilogue(const float* __restrict__ part, const float* __restrict__ bias,
                           short* __restrict__ out_b, float* __restrict__ out_f,
                           int MN, int N, int S, float slope) {
    int i = (blockIdx.x * 256 + threadIdx.x) * 4;
    if (i >= MN) return;
    float4 v = *(const float4*)(part + i);
    for (int s = 1; s < S; ++s) {
        float4 p = *(const float4*)(part + (size_t)s * MN + i);
        v.x += p.x; v.y += p.y; v.z += p.z; v.w += p.w;
    }
    float4 b = *(const float4*)(bias + (i % N));
    v.x += b.x; v.y += b.y; v.z += b.z; v.w += b.w;
    v.x = (v.x >= 0.f) ? v.x : v.x * slope;
    v.y = (v.y >= 0.f) ? v.y : v.y * slope;
    v.z = (v.z >= 0.f) ? v.z : v.z * slope;
    v.w = (v.w >= 0.f) ? v.w : v.w * slope;
    if (out_b) {
        out_b[i + 0] = f2bs(v.x); out_b[i + 1] = f2bs(v.y);
        out_b[i + 2] = f2bs(v.z); out_b[i + 3] = f2bs(v.w);
    }
    if (out_f) *(float4*)(out_f + i) = v;
}

// ---------------- GEMM with fused bias+leaky epilogue (BK=64) ----------------
__global__ void k_gemm_bias(const short* __restrict__ A, const short* __restrict__ W,
                            const float* __restrict__ bias, short* __restrict__ out_b,
                            float* __restrict__ out_f, int M, int N, int K, float slope) {
    __shared__ short As[2][64 * 40];
    __shared__ short Ws[2][64 * 40];
    const int tid = threadIdx.x;
    const int m0 = blockIdx.y * 64, n0 = blockIdx.x * 64;
    const int w = tid >> 6, l = tid & 63;
    const int wr = w >> 1, wc = w & 1;
    const int sr = tid >> 2, sc = tid & 3;
    const int lr = l & 15, lg = l >> 4;
    f32x4 acc[2][2] = {};
    for (int k0 = 0; k0 < K; k0 += 64) {
        short8 av0 = *(const short8*)(A + (size_t)(m0 + sr) * K + k0 + sc * 8);
        short8 av1 = *(const short8*)(A + (size_t)(m0 + sr) * K + k0 + 32 + sc * 8);
        short8 wv0 = *(const short8*)(W + (size_t)(n0 + sr) * K + k0 + sc * 8);
        short8 wv1 = *(const short8*)(W + (size_t)(n0 + sr) * K + k0 + 32 + sc * 8);
        __syncthreads();
        *(short8*)&As[0][sr * 40 + sc * 8] = av0;
        *(short8*)&As[1][sr * 40 + sc * 8] = av1;
        *(short8*)&Ws[0][sr * 40 + sc * 8] = wv0;
        *(short8*)&Ws[1][sr * 40 + sc * 8] = wv1;
        __syncthreads();
        int cb = lg * 8;
#pragma unroll
        for (int h = 0; h < 2; ++h) {
            short8 a0 = *(const short8*)&As[h][(wr * 32 + lr) * 40 + cb];
            short8 a1 = *(const short8*)&As[h][(wr * 32 + 16 + lr) * 40 + cb];
            short8 b0 = *(const short8*)&Ws[h][(wc * 32 + lr) * 40 + cb];
            short8 b1 = *(const short8*)&Ws[h][(wc * 32 + 16 + lr) * 40 + cb];
            acc[0][0] = MFMA16(a0, b0, acc[0][0]);
            acc[0][1] = MFMA16(a0, b1, acc[0][1]);
            acc[1][0] = MFMA16(a1, b0, acc[1][0]);
            acc[1][1] = MFMA16(a1, b1, acc[1][1]);
        }
    }
#pragma unroll
    for (int mi = 0; mi < 2; ++mi)
#pragma unroll
        for (int ni = 0; ni < 2; ++ni)
#pragma unroll
            for (int j = 0; j < 4; ++j) {
                int row = m0 + wr * 32 + mi * 16 + lg * 4 + j;
                int col = n0 + wc * 32 + ni * 16 + lr;
                float v = acc[mi][ni][j] + bias[col];
                v = (v >= 0.f) ? v : v * slope;
                if (out_f) out_f[(size_t)row * N + col] = v;
                else       out_b[(size_t)row * N + col] = f2bs(v);
            }
}

// ---------------- persistent LSTM v4 (best known: 82 µs — structural floor) ----------------
__global__ void __launch_bounds__(1024) k_lstm_all4(
        const float* __restrict__ P, const short* __restrict__ Whhb,
        const int* __restrict__ done, u64* __restrict__ hq0, u64* __restrict__ hq1,
        const float* __restrict__ c0, short* __restrict__ nh,
        float* __restrict__ outH, float* __restrict__ outC, unsigned* __restrict__ flags) {
    __shared__ short hs[32 * 520];      // h staging [32 batch][512+8]
    __shared__ float gb[4 * 32 * 33];   // gates [gate][unit_local][batch] padded
    __shared__ short ch[32 * 33];       // h-chunk [unit_local][batch] padded
    const int b = blockIdx.x;
    const int tid = threadIdx.x;
    const int w = tid >> 6, l = tid & 63, lr = l & 15, lg = l >> 4;
    const int mt = w & 1, nt = w >> 1;
    const int r = nt * 16 + lr;                  // gate-local row 0..127
    const int gate = r >> 5, ul = r & 31;
    const int G = gate * 512 + b * 32 + ul;      // global gate row
    short8 bfg[16];
    const short* wrow = Whhb + (size_t)G * 512;
#pragma unroll
    for (int ks = 0; ks < 16; ++ks) bfg[ks] = *(const short8*)(wrow + ks * 32 + lg * 8);
    const int cu = tid >> 5, cb = tid & 31;
    float cr = c0[cb * 512 + b * 32 + cu];
    const int pb = tid >> 3;
    unsigned dmC = 0, dmP = 0;
#pragma unroll
    for (int q = 0; q < 16; ++q) {
        dmC |= (done[q * 32 + cb] ? 1u : 0u) << q;
        dmP |= (done[q * 32 + pb] ? 1u : 0u) << q;
    }
    float pr[4];
#pragma unroll
    for (int j = 0; j < 4; ++j)
        pr[j] = P[(size_t)(mt * 16 + lg * 4 + j) * 2048 + G];

    for (int t = 0; t < 16; ++t) {
        const u64* hin = (t & 1) ? hq1 : hq0;
        u64* hout      = (t & 1) ? hq0 : hq1;
        if (t > 0) {
            if (tid < 16) {
                while (__hip_atomic_load(flags + tid, __ATOMIC_RELAXED,
                                         __HIP_MEMORY_SCOPE_AGENT) < (unsigned)t)
                    __builtin_amdgcn_s_sleep(1);
            }
            __syncthreads();
        }
#pragma unroll
        for (int it = 0; it < 4; ++it) {
            int i = it * 1024 + tid;
            u64 g = __hip_atomic_load(hin + i, __ATOMIC_RELAXED, __HIP_MEMORY_SCOPE_AGENT);
            *(u64*)&hs[(i >> 7) * 520 + (i & 127) * 4] = g;
        }
        __syncthreads();
        f32x4 acc = {};
#pragma unroll
        for (int ks = 0; ks < 16; ++ks) {
            short8 a = *(const short8*)&hs[(mt * 16 + lr) * 520 + ks * 32 + lg * 8];
            acc = MFMA16(a, bfg[ks], acc);
        }
#pragma unroll
        for (int j = 0; j < 4; ++j)
            gb[gate * 1056 + ul * 33 + (mt * 16 + lg * 4 + j)] = acc[j] + pr[j];
        __syncthreads();
        {
            float gi = gb[0 * 1056 + cu * 33 + cb];
            float gf = gb[1 * 1056 + cu * 33 + cb];
            float gg = gb[2 * 1056 + cu * 33 + cb];
            float go = gb[3 * 1056 + cu * 33 + cb];
            float m = ((dmC >> t) & 1u) ? 0.f : 1.f;
            float ig = 1.f / (1.f + expf(-gi));
            float fg = 1.f / (1.f + expf(-gf));
            float gt = tanhf(gg);
            float og = 1.f / (1.f + expf(-go));
            float cn = fg * (cr * m) + ig * gt;
            float hn = og * tanhf(cn);
            cr = cn;
            ch[cu * 33 + cb] = f2bs(hn);
            if (t == 15) {
                outH[cb * 512 + b * 32 + cu] = hn;
                outC[cb * 512 + b * 32 + cu] = cn;
            }
        }
        __syncthreads();
        if (t < 15) {
            if (tid < 256) {
                int bb3 = tid >> 3, uq = (tid & 7) * 4;
                u64 q = 0;
                if (!((dmP >> (t + 1)) & 1u)) {
                    unsigned lo = ((unsigned)(unsigned short)ch[uq * 33 + bb3]) |
                                  (((unsigned)(unsigned short)ch[(uq + 1) * 33 + bb3]) << 16);
                    unsigned hi = ((unsigned)(unsigned short)ch[(uq + 2) * 33 + bb3]) |
                                  (((unsigned)(unsigned short)ch[(uq + 3) * 33 + bb3]) << 16);
                    q = (u64)lo | ((u64)hi << 32);
                }
                __hip_atomic_store(hout + bb3 * 128 + b * 8 + (tid & 7), q,
                                   __ATOMIC_RELAXED, __HIP_MEMORY_SCOPE_AGENT);
            }
            asm volatile("s_waitcnt vmcnt(0)" ::: "memory");
            __syncthreads();
            if (tid == 0)
                __hip_atomic_store(flags + b, (unsigned)(t + 1),
                                   __ATOMIC_RELAXED, __HIP_MEMORY_SCOPE_AGENT);
        }
        if (tid < 512) {
            int bb2 = tid >> 4, up = (tid & 15) * 2;
            unsigned pkv = ((unsigned)(unsigned short)ch[up * 33 + bb2]) |
                           (((unsigned)(unsigned short)ch[(up + 1) * 33 + bb2]) << 16);
            *(unsigned*)&nh[(size_t)(t * 32 + bb2) * 512 + b * 32 + up] = pkv;
        }
        int tp = (t < 15) ? t + 1 : 15;
#pragma unroll
        for (int j = 0; j < 4; ++j)
            pr[j] = P[(size_t)(tp * 32 + mt * 16 + lg * 4 + j) * 2048 + G];
    }
}

// ---------------- small heads: logits [512][8] + value [512] ----------------
__global__ void k_heads(const short* __restrict__ aAC,
                        const short* __restrict__ A2b, const float* __restrict__ Ab2,
                        const short* __restrict__ C2b, const float* __restrict__ Cb2,
                        float* __restrict__ out) {
    int idx = blockIdx.x * 4 + (threadIdx.x >> 6);
    int l = threadIdx.x & 63;
    if (idx >= 4608) return;
    int row = idx / 9, col = idx % 9;
    const short* act = aAC + (size_t)row * 1024 + (col < 8 ? 0 : 512);
    const short* wr  = (col < 8) ? (A2b + (size_t)col * 512) : C2b;
    short8 a = *(const short8*)(act + l * 8);
    short8 wv = *(const short8*)(wr + l * 8);
    float s = 0.f;
#pragma unroll
    for (int q = 0; q < 8; ++q) s += bs2f(a[q]) * bs2f(wv[q]);
#pragma unroll
    for (int off = 32; off > 0; off >>= 1) s += __shfl_xor(s, off, 64);
    if (l == 0) {
        if (col < 8) out[row * 8 + col] = s + Ab2[col];
        else out[4096 + row] = s + Cb2[0];
    }
}

// ---------------- launch ----------------

extern "C" void kernel_launch(void* const* d_in, const int* in_sizes, int n_in,
                              void* d_out, int out_size, void* d_ws, size_t ws_size,
                              hipStream_t stream) {
    (void)in_sizes; (void)n_in; (void)out_size; (void)ws_size;
    const float* x    = (const float*)d_in[0];
    const int*   done = (const int*)  d_in[1];
    const float* h0   = (const float*)d_in[2];
    const float* c0   = (const float*)d_in[3];
    const float* w1   = (const float*)d_in[4];
    const float* b1   = (const float*)d_in[5];
    const float* w2   = (const float*)d_in[6];
    const float* b2   = (const float*)d_in[7];
    const float* w3   = (const float*)d_in[8];
    const float* b3   = (const float*)d_in[9];
    const float* fcW  = (const float*)d_in[10];
    const float* fcb  = (const float*)d_in[11];
    const float* Wih  = (const float*)d_in[12];
    const float* Whh  = (const float*)d_in[13];
    const float* bih  = (const float*)d_in[14];
    const float* bhh  = (const float*)d_in[15];
    const float* A1   = (const float*)d_in[16];
    const float* Ab1  = (const float*)d_in[17];
    const float* A2   = (const float*)d_in[18];
    const float* Ab2  = (const float*)d_in[19];
    const float* C1   = (const float*)d_in[20];
    const float* Cb1  = (const float*)d_in[21];
    const float* C2   = (const float*)d_in[22];
    const float* Cb2  = (const float*)d_in[23];
    float* out = (float*)d_out;

    char* wsp = (char*)d_ws;
    auto alloc = [&](size_t bytes) {
        char* p = wsp; wsp += (bytes + 255) & ~(size_t)255; return p;
    };
    short* a3s  = (short*)alloc(5767168ull * 2);   // [512*176][64]
    short* hfc  = (short*)alloc(262144ull * 2);    // [512][512]
    float* P    = (float*)alloc(1048576ull * 4);   // [512][2048]
    short* whhb = (short*)alloc(1048576ull * 2);   // Whh bf16 [2048][512]
    u64*   hq0  = (u64*)  alloc(16384ull * 2);     // masked h, qword view
    u64*   hq1  = (u64*)  alloc(16384ull * 2);
    short* nh   = (short*)alloc(262144ull * 2);
    short* aAC  = (short*)alloc(524288ull * 2);    // [512][1024]
    float* part = (float*)alloc(2097152ull * 4);   // FC split-K 8 partials (8 MB)
    short* wc1  = (short*)alloc(6144ull * 2);
    short* wc2  = (short*)alloc(32768ull * 2);
    short* wc3  = (short*)alloc(36864ull * 2);
    short* fcwr = (short*)alloc(5767168ull * 2);
    short* wihb = (short*)alloc(1048576ull * 2);
    short* a1b  = (short*)alloc(262144ull * 2);
    short* c1b  = (short*)alloc(262144ull * 2);
    short* a2b  = (short*)alloc(4096ull * 2);
    short* c2b  = (short*)alloc(512ull * 2);
    float* bias2  = (float*)alloc(2048ull * 4);
    float* biasAC = (float*)alloc(1024ull * 4);
    unsigned* flags = (unsigned*)alloc(256);

    // all prep in one launch
    k_megaprep<<<3432, 256, 0, stream>>>(w1, w2, w3, fcW, Wih, Whh, A1, C1, A2, C2,
                                         h0, done, bih, bhh, Ab1, Cb1,
                                         wc1, wc2, wc3, fcwr, wihb, whhb,
                                         a1b, c1b, a2b, c2b, (short*)hq0,
                                         bias2, biasAC, flags);

    // fused conv1+conv2+conv3 with ring buffer (2 blocks/CU)
    k_conv123<<<512, 256, 0, stream>>>(x, wc1, b1, wc2, b2, wc3, b3, a3s);

    // FC: split-K 8 + epilogue
    k_gemm_mfma<<<dim3(8, 8, 8), 256, 0, stream>>>(a3s, fcwr, part, 512, 512, 11264, 1408);
    k_epilogue<<<256, 256, 0, stream>>>(part, fcb, hfc, nullptr, 262144, 512, 8, 0.2f);

    // P = hfc @ Wih^T + (bih + bhh)  (fused epilogue, f32 out)
    k_gemm_bias<<<dim3(32, 8), 256, 0, stream>>>(hfc, wihb, bias2, nullptr, P,
                                                 512, 2048, 512, 1.0f);

    // LSTM: one persistent launch (v4, best known)
    k_lstm_all4<<<16, 1024, 0, stream>>>(P, whhb, done, hq0, hq1, c0, nh,
                                         out + 4608, out + 20992, flags);

    // heads: combined [A1;C1] GEMM (fused epilogue, bf16 out)
    k_gemm_bias<<<dim3(16, 8), 256, 0, stream>>>(nh, a1b, biasAC, aAC, nullptr,
                                                 512, 1024, 512, 0.01f);
    k_heads<<<1152, 256, 0, stream>>>(aAC, a2b, Ab2, c2b, Cb2, out);
}

// Round 16
// 201.117 us; speedup vs baseline: 1.0311x; 1.0311x over previous
//
#include <hip/hip_runtime.h>
#include <hip/hip_bf16.h>
#include <math.h>

using short8 = __attribute__((ext_vector_type(8))) short;   // 8 bf16 (4 VGPR)
using f32x4  = __attribute__((ext_vector_type(4))) float;   // MFMA acc
typedef unsigned long long u64;

#define MFMA16(a, b, c) __builtin_amdgcn_mfma_f32_16x16x32_bf16(a, b, c, 0, 0, 0)

__device__ __forceinline__ short f2bs(float f) {
    __hip_bfloat16 h = __float2bfloat16(f);          // RNE
    return __builtin_bit_cast(short, h);
}
__device__ __forceinline__ float bs2f(short s) {
    return __uint_as_float(((unsigned)(unsigned short)s) << 16);
}

// ---------------- mega-prep: all weight conversions + transposes in ONE launch ----------------
__global__ void __launch_bounds__(256) k_megaprep(
        const float* __restrict__ w1, const float* __restrict__ w2,
        const float* __restrict__ w3, const float* __restrict__ fcW,
        const float* __restrict__ Wih, const float* __restrict__ Whh,
        const float* __restrict__ A1, const float* __restrict__ C1,
        const float* __restrict__ A2, const float* __restrict__ C2,
        const float* __restrict__ h0, const int* __restrict__ done,
        const float* __restrict__ bih, const float* __restrict__ bhh,
        const float* __restrict__ Ab1, const float* __restrict__ Cb1,
        short* __restrict__ wc1, short* __restrict__ wc2, short* __restrict__ wc3,
        short* __restrict__ fcwr, short* __restrict__ wihb, short* __restrict__ whhb,
        short* __restrict__ a1b, short* __restrict__ c1b, short* __restrict__ a2b,
        short* __restrict__ c2b, short* __restrict__ hm0,
        float* __restrict__ bias2, float* __restrict__ biasAC, unsigned* __restrict__ flags) {
    __shared__ short t[176 * 76];
    const int bid = blockIdx.x, tid = threadIdx.x;

    auto cvt4 = [&](const float* in, short* out, int i) {
        float4 v = *(const float4*)(in + i * 4);
        out[i * 4 + 0] = f2bs(v.x); out[i * 4 + 1] = f2bs(v.y);
        out[i * 4 + 2] = f2bs(v.z); out[i * 4 + 3] = f2bs(v.w);
    };

    if (bid < 512) {
        // fcW [512][11264] (K = oc*176+pix) -> fcwr [512][pix*64+oc]
        int r = bid;
        for (int it = 0; it < 11; ++it) {
            int c4 = it * 256 + tid;
            float4 v = *(const float4*)(fcW + (size_t)r * 11264 + c4 * 4);
            int c = c4 * 4;
            int oc = c / 176, pix = c % 176;
            t[(pix + 0) * 76 + oc] = f2bs(v.x);
            t[(pix + 1) * 76 + oc] = f2bs(v.y);
            t[(pix + 2) * 76 + oc] = f2bs(v.z);
            t[(pix + 3) * 76 + oc] = f2bs(v.w);
        }
        __syncthreads();
        for (int it = 0; it < 6; ++it) {
            int j8 = it * 256 + tid;
            if (j8 < 1408) {
                int j = j8 * 8, pix = j >> 6, oc0 = j & 63;
                const short* tp = &t[pix * 76 + oc0];
                short8 v;
                ((uint2*)&v)[0] = *(const uint2*)tp;
                ((uint2*)&v)[1] = *(const uint2*)(tp + 4);
                *(short8*)&fcwr[(size_t)r * 11264 + j] = v;
            }
        }
    } else if (bid < 1536) {
        cvt4(Wih, wihb, (bid - 512) * 256 + tid);
    } else if (bid < 2560) {
        cvt4(Whh, whhb, (bid - 1536) * 256 + tid);
    } else if (bid < 2816) {
        cvt4(A1, a1b, (bid - 2560) * 256 + tid);
    } else if (bid < 3072) {
        cvt4(C1, c1b, (bid - 2816) * 256 + tid);
    } else if (bid < 3078) {
        cvt4(w1, wc1, (bid - 3072) * 256 + tid);       // layout already (ic*64+kh*8+kw)
    } else if (bid < 3206) {
        int i = (bid - 3078) * 256 + tid;              // 32768
        int oc = i >> 9, col = i & 511;
        int kh = col >> 7, kw = (col >> 5) & 3, ic = col & 31;
        wc2[i] = f2bs(w2[((oc * 32 + ic) * 4 + kh) * 4 + kw]);
    } else if (bid < 3350) {
        int i = (bid - 3206) * 256 + tid;              // 36864
        int oc = i / 576, col = i % 576;
        int kh = col / 192, r = col % 192, kw = r >> 6, ic = r & 63;
        wc3[i] = f2bs(w3[((oc * 64 + ic) * 3 + kh) * 3 + kw]);
    } else if (bid < 3354) {
        cvt4(A2, a2b, (bid - 3350) * 256 + tid);
    } else if (bid < 3355) {
        if (tid < 128) cvt4(C2, c2b, tid);
    } else if (bid < 3419) {
        int i = (bid - 3355) * 256 + tid;              // 16384
        float m = 1.f - (float)done[i >> 9];
        hm0[i] = f2bs(h0[i] * m);
    } else if (bid < 3427) {
        int i = (bid - 3419) * 256 + tid;              // 2048
        bias2[i] = bih[i] + bhh[i];
    } else if (bid < 3431) {
        int i = (bid - 3427) * 256 + tid;              // 1024
        biasAC[i] = (i < 512) ? Ab1[i] : Cb1[i - 512];
    } else {
        if (tid < 16) flags[tid] = 0u;
    }
}

// ---------------- fused conv1+conv2+conv3 (512 threads / 8 waves, min-occ 2 waves/EU) ----------------
// a1 lives only in LDS (img1, swizzled); a2 only in LDS (img2). ~108 KB LDS, 1 block/CU.
// __launch_bounds__(512, 2): exactly one 8-wave block/CU resident -> allocator may use
// up to 256 VGPR, keeping the conv1 fA/fB prefetch pipeline in registers (round-14 fix).
__global__ void __launch_bounds__(512, 2) k_conv123(
        const float* __restrict__ x,   const short* __restrict__ Wc1,
        const float* __restrict__ b1,
        const short* __restrict__ Wc2, const float* __restrict__ b2,
        const short* __restrict__ Wc3, const float* __restrict__ b3,
        short* __restrict__ y3) {
    __shared__ short img1[36192];       // [1131 px][32 oc] swizzled (conv1 out / conv2 in)
    __shared__ short img2[14976];       // [13][18][64] swizzled (conv2 out / conv3 in)
    __shared__ short ct[4096];          // conv1: [8 waves][16px][32oc]; conv2/3: [4 pairs][16px][64oc]
    const int n = blockIdx.x, tid = threadIdx.x;
    const int w = tid >> 6, l = tid & 63, lr = l & 15, lg = l >> 4;
    const int par = w >> 1, nfh = w & 1;           // 4 wave-pairs for conv2/3

    // ---- conv1 phase: x[n] (f32, HBM/L3) -> img1 (bf16 LDS, swizzled a1 layout) ----
    {
        short8 bf[6][2];
#pragma unroll
        for (int ks = 0; ks < 6; ++ks)
#pragma unroll
            for (int nf = 0; nf < 2; ++nf)
                bf[ks][nf] = *(const short8*)&Wc1[(nf * 16 + lr) * 192 + ks * 32 + lg * 8];
        const float bc0 = b1[lr], bc1 = b1[16 + lr];
        const float* xb = x + (size_t)n * 57600;
        auto tileBase = [&](int tt) -> const float* {
            int p = tt * 16 + lr; if (p > 1130) p = 1130;
            int oh = p / 39, ow = p - oh * 39;
            return xb + (oh * 4) * 160 + ow * 4;
        };
        // tiles tt = i*8 + w, tt <= 70: w<=6 -> 9 tiles, w==7 -> 8 tiles
        const int ntiles = (w <= 6) ? 9 : 8;
        float4 fA[6][2], fB[6][2];
        {
            const float* base = tileBase(w);
#pragma unroll
            for (int ks = 0; ks < 6; ++ks) {
                int ic = ks >> 1, kh = (ks & 1) * 4 + lg;
                const float* ap = base + ic * 19200 + kh * 160;
                fA[ks][0] = *(const float4*)ap;
                fA[ks][1] = *(const float4*)(ap + 4);
            }
        }
        for (int i = 0; i < ntiles; ++i) {
            const int tt = i * 8 + w;
            if (i + 1 < ntiles) {                        // prefetch next tile
                const float* nb = tileBase(tt + 8);
#pragma unroll
                for (int ks = 0; ks < 6; ++ks) {
                    int ic = ks >> 1, kh = (ks & 1) * 4 + lg;
                    const float* ap = nb + ic * 19200 + kh * 160;
                    fB[ks][0] = *(const float4*)ap;
                    fB[ks][1] = *(const float4*)(ap + 4);
                }
            }
            f32x4 acc[2] = {};
#pragma unroll
            for (int ks = 0; ks < 6; ++ks) {
                short8 a;
                a[0] = f2bs(fA[ks][0].x); a[1] = f2bs(fA[ks][0].y);
                a[2] = f2bs(fA[ks][0].z); a[3] = f2bs(fA[ks][0].w);
                a[4] = f2bs(fA[ks][1].x); a[5] = f2bs(fA[ks][1].y);
                a[6] = f2bs(fA[ks][1].z); a[7] = f2bs(fA[ks][1].w);
                acc[0] = MFMA16(a, bf[ks][0], acc[0]);
                acc[1] = MFMA16(a, bf[ks][1], acc[1]);
            }
#pragma unroll
            for (int j = 0; j < 4; ++j) {
                ct[w * 512 + (lg * 4 + j) * 32 + lr] = f2bs(fmaxf(acc[0][j] + bc0, 0.f));
                ct[w * 512 + (lg * 4 + j) * 32 + 16 + lr] = f2bs(fmaxf(acc[1][j] + bc1, 0.f));
            }
            asm volatile("s_waitcnt lgkmcnt(0)" ::: "memory");
            {
                int row = l >> 2, c8 = (l & 3) * 8;
                int pg = tt * 16 + row;
                if (pg < 1131) {
                    short8 v = *(const short8*)&ct[w * 512 + row * 32 + c8];
                    int b = pg * 64 + c8 * 2;            // linear byte offset in a1 layout
                    b ^= ((b >> 7) & 7) << 4;            // img1 swizzle (matches conv2 reads)
                    *(short8*)((char*)img1 + b) = v;
                }
            }
            asm volatile("s_waitcnt lgkmcnt(0)" ::: "memory");
            if (i + 1 < ntiles) {
#pragma unroll
                for (int ks = 0; ks < 6; ++ks) {
                    fA[ks][0] = fB[ks][0];
                    fA[ks][1] = fB[ks][1];
                }
            }
        }
    }
    __syncthreads();

    // ---- conv2 phase: img1 -> img2 (4 wave-pairs over 16 m-tiles) ----
    {
        short8 bfg[16][2];
#pragma unroll
        for (int ks = 0; ks < 16; ++ks)
#pragma unroll
            for (int q2 = 0; q2 < 2; ++q2)
                bfg[ks][q2] = *(const short8*)&Wc2[(nfh * 32 + q2 * 16 + lr) * 512 + ks * 32 + lg * 8];
        float bc[2] = {b2[nfh * 32 + lr], b2[nfh * 32 + 16 + lr]};
        for (int t = par; t < 16; t += 4) {
            int p = t * 16 + lr;
            int pc = p < 234 ? p : 233;
            int oh = pc / 18, ow = pc - oh * 18;
            int base = (oh * 2 * 39 + ow * 2) * 64 + lg * 16;
            f32x4 acc[2] = {};
#pragma unroll
            for (int ks = 0; ks < 16; ++ks) {
                int kh = ks >> 2, kw = ks & 3;
                int b = base + (kh * 39 + kw) * 64;
                b ^= ((b >> 7) & 7) << 4;
                short8 a = *(const short8*)((const char*)img1 + b);
                acc[0] = MFMA16(a, bfg[ks][0], acc[0]);
                acc[1] = MFMA16(a, bfg[ks][1], acc[1]);
            }
#pragma unroll
            for (int q2 = 0; q2 < 2; ++q2)
#pragma unroll
                for (int j = 0; j < 4; ++j)
                    ct[par * 1024 + (lg * 4 + j) * 64 + nfh * 32 + q2 * 16 + lr] =
                        f2bs(fmaxf(acc[q2][j] + bc[q2], 0.f));
            __syncthreads();
            int li = nfh * 64 + l;
            int row = li >> 3, c8 = (li & 7) * 8;
            short8 v = *(const short8*)&ct[par * 1024 + row * 64 + c8];
            int pg = t * 16 + row;
            if (pg < 234) {
                int b = (pg * 64 + c8) * 2;              // byte offset in img2
                b ^= ((b >> 7) & 7) << 4;
                *(short8*)((char*)img2 + b) = v;
            }
            __syncthreads();
        }
    }
    __syncthreads();

    // ---- conv3 phase: img2 -> a3 (global), 4 wave-pairs over 12 m-tiles ----
    {
        short8 bfg[18][2];
#pragma unroll
        for (int ks = 0; ks < 18; ++ks)
#pragma unroll
            for (int q2 = 0; q2 < 2; ++q2)
                bfg[ks][q2] = *(const short8*)&Wc3[(nfh * 32 + q2 * 16 + lr) * 576 + ks * 32 + lg * 8];
        float bc[2] = {b3[nfh * 32 + lr], b3[nfh * 32 + 16 + lr]};
        for (int t = par; t < 12; t += 4) {
            int p = t * 16 + lr;
            int pc = p < 176 ? p : 175;
            int oh = pc >> 4, ow = pc & 15;
            int base = (oh * 18 + ow) * 128 + lg * 16;
            f32x4 acc[2] = {};
#pragma unroll
            for (int ks = 0; ks < 18; ++ks) {
                int kh = ks / 6, r6 = ks % 6, kw = r6 >> 1, ich = r6 & 1;
                int b = base + (kh * 18 + kw) * 128 + ich * 64;
                b ^= ((b >> 7) & 7) << 4;
                short8 a = *(const short8*)((const char*)img2 + b);
                acc[0] = MFMA16(a, bfg[ks][0], acc[0]);
                acc[1] = MFMA16(a, bfg[ks][1], acc[1]);
            }
#pragma unroll
            for (int q2 = 0; q2 < 2; ++q2)
#pragma unroll
                for (int j = 0; j < 4; ++j)
                    ct[par * 1024 + (lg * 4 + j) * 64 + nfh * 32 + q2 * 16 + lr] =
                        f2bs(fmaxf(acc[q2][j] + bc[q2], 0.f));
            __syncthreads();
            int li = nfh * 64 + l;
            int row = li >> 3, c8 = (li & 7) * 8;
            short8 v = *(const short8*)&ct[par * 1024 + row * 64 + c8];
            int pg = t * 16 + row;
            if (pg < 176)
                *(short8*)&y3[((size_t)n * 176 + pg) * 64 + c8] = v;
            __syncthreads();
        }
    }
}

// ---------------- MFMA GEMM core (BK=64): part[z][M][N] = A @ W^T ----------------
__global__ void k_gemm_mfma(const short* __restrict__ A, const short* __restrict__ W,
                            float* __restrict__ part, int M, int N, int K, int kPerSplit) {
    __shared__ short As[2][64 * 40];
    __shared__ short Ws[2][64 * 40];
    const int tid = threadIdx.x;
    const int m0 = blockIdx.y * 64, n0 = blockIdx.x * 64;
    const int k0s = blockIdx.z * kPerSplit, k0e = k0s + kPerSplit;
    const int w = tid >> 6, l = tid & 63;
    const int wr = w >> 1, wc = w & 1;
    const int sr = tid >> 2, sc = tid & 3;
    const int lr = l & 15, lg = l >> 4;
    f32x4 acc[2][2] = {};
    for (int k0 = k0s; k0 < k0e; k0 += 64) {
        short8 av0 = *(const short8*)(A + (size_t)(m0 + sr) * K + k0 + sc * 8);
        short8 av1 = *(const short8*)(A + (size_t)(m0 + sr) * K + k0 + 32 + sc * 8);
        short8 wv0 = *(const short8*)(W + (size_t)(n0 + sr) * K + k0 + sc * 8);
        short8 wv1 = *(const short8*)(W + (size_t)(n0 + sr) * K + k0 + 32 + sc * 8);
        __syncthreads();
        *(short8*)&As[0][sr * 40 + sc * 8] = av0;
        *(short8*)&As[1][sr * 40 + sc * 8] = av1;
        *(short8*)&Ws[0][sr * 40 + sc * 8] = wv0;
        *(short8*)&Ws[1][sr * 40 + sc * 8] = wv1;
        __syncthreads();
        int cb = lg * 8;
#pragma unroll
        for (int h = 0; h < 2; ++h) {
            short8 a0 = *(const short8*)&As[h][(wr * 32 + lr) * 40 + cb];
            short8 a1 = *(const short8*)&As[h][(wr * 32 + 16 + lr) * 40 + cb];
            short8 b0 = *(const short8*)&Ws[h][(wc * 32 + lr) * 40 + cb];
            short8 b1 = *(const short8*)&Ws[h][(wc * 32 + 16 + lr) * 40 + cb];
            acc[0][0] = MFMA16(a0, b0, acc[0][0]);
            acc[0][1] = MFMA16(a0, b1, acc[0][1]);
            acc[1][0] = MFMA16(a1, b0, acc[1][0]);
            acc[1][1] = MFMA16(a1, b1, acc[1][1]);
        }
    }
    float* pp = part + (size_t)blockIdx.z * M * N;
#pragma unroll
    for (int mi = 0; mi < 2; ++mi)
#pragma unroll
        for (int ni = 0; ni < 2; ++ni)
#pragma unroll
            for (int j = 0; j < 4; ++j) {
                int row = m0 + wr * 32 + mi * 16 + lg * 4 + j;
                int col = n0 + wc * 32 + ni * 16 + lr;
                pp[(size_t)row * N + col] = acc[mi][ni][j];
            }
}

// FC epilogue: sum splits + bias + leaky -> bf16/f32
__global__ void k_epilogue(const float* __restrict__ part, const float* __restrict__ bias,
                           short* __restrict__ out_b, float* __restrict__ out_f,
                           int MN, int N, int S, float slope) {
    int i = (blockIdx.x * 256 + threadIdx.x) * 4;
    if (i >= MN) return;
    float4 v = *(const float4*)(part + i);
    for (int s = 1; s < S; ++s) {
        float4 p = *(const float4*)(part + (size_t)s * MN + i);
        v.x += p.x; v.y += p.y; v.z += p.z; v.w += p.w;
    }
    float4 b = *(const float4*)(bias + (i % N));
    v.x += b.x; v.y += b.y; v.z += b.z; v.w += b.w;
    v.x = (v.x >= 0.f) ? v.x : v.x * slope;
    v.y = (v.y >= 0.f) ? v.y : v.y * slope;
    v.z = (v.z >= 0.f) ? v.z : v.z * slope;
    v.w = (v.w >= 0.f) ? v.w : v.w * slope;
    if (out_b) {
        out_b[i + 0] = f2bs(v.x); out_b[i + 1] = f2bs(v.y);
        out_b[i + 2] = f2bs(v.z); out_b[i + 3] = f2bs(v.w);
    }
    if (out_f) *(float4*)(out_f + i) = v;
}

// ---------------- GEMM with fused bias+leaky epilogue (BK=64) ----------------
__global__ void k_gemm_bias(const short* __restrict__ A, const short* __restrict__ W,
                            const float* __restrict__ bias, short* __restrict__ out_b,
                            float* __restrict__ out_f, int M, int N, int K, float slope) {
    __shared__ short As[2][64 * 40];
    __shared__ short Ws[2][64 * 40];
    const int tid = threadIdx.x;
    const int m0 = blockIdx.y * 64, n0 = blockIdx.x * 64;
    const int w = tid >> 6, l = tid & 63;
    const int wr = w >> 1, wc = w & 1;
    const int sr = tid >> 2, sc = tid & 3;
    const int lr = l & 15, lg = l >> 4;
    f32x4 acc[2][2] = {};
    for (int k0 = 0; k0 < K; k0 += 64) {
        short8 av0 = *(const short8*)(A + (size_t)(m0 + sr) * K + k0 + sc * 8);
        short8 av1 = *(const short8*)(A + (size_t)(m0 + sr) * K + k0 + 32 + sc * 8);
        short8 wv0 = *(const short8*)(W + (size_t)(n0 + sr) * K + k0 + sc * 8);
        short8 wv1 = *(const short8*)(W + (size_t)(n0 + sr) * K + k0 + 32 + sc * 8);
        __syncthreads();
        *(short8*)&As[0][sr * 40 + sc * 8] = av0;
        *(short8*)&As[1][sr * 40 + sc * 8] = av1;
        *(short8*)&Ws[0][sr * 40 + sc * 8] = wv0;
        *(short8*)&Ws[1][sr * 40 + sc * 8] = wv1;
        __syncthreads();
        int cb = lg * 8;
#pragma unroll
        for (int h = 0; h < 2; ++h) {
            short8 a0 = *(const short8*)&As[h][(wr * 32 + lr) * 40 + cb];
            short8 a1 = *(const short8*)&As[h][(wr * 32 + 16 + lr) * 40 + cb];
            short8 b0 = *(const short8*)&Ws[h][(wc * 32 + lr) * 40 + cb];
            short8 b1 = *(const short8*)&Ws[h][(wc * 32 + 16 + lr) * 40 + cb];
            acc[0][0] = MFMA16(a0, b0, acc[0][0]);
            acc[0][1] = MFMA16(a0, b1, acc[0][1]);
            acc[1][0] = MFMA16(a1, b0, acc[1][0]);
            acc[1][1] = MFMA16(a1, b1, acc[1][1]);
        }
    }
#pragma unroll
    for (int mi = 0; mi < 2; ++mi)
#pragma unroll
        for (int ni = 0; ni < 2; ++ni)
#pragma unroll
            for (int j = 0; j < 4; ++j) {
                int row = m0 + wr * 32 + mi * 16 + lg * 4 + j;
                int col = n0 + wc * 32 + ni * 16 + lr;
                float v = acc[mi][ni][j] + bias[col];
                v = (v >= 0.f) ? v : v * slope;
                if (out_f) out_f[(size_t)row * N + col] = v;
                else       out_b[(size_t)row * N + col] = f2bs(v);
            }
}

// ---------------- persistent LSTM v4 (best known: 82 µs — structural floor) ----------------
__global__ void __launch_bounds__(1024) k_lstm_all4(
        const float* __restrict__ P, const short* __restrict__ Whhb,
        const int* __restrict__ done, u64* __restrict__ hq0, u64* __restrict__ hq1,
        const float* __restrict__ c0, short* __restrict__ nh,
        float* __restrict__ outH, float* __restrict__ outC, unsigned* __restrict__ flags) {
    __shared__ short hs[32 * 520];      // h staging [32 batch][512+8]
    __shared__ float gb[4 * 32 * 33];   // gates [gate][unit_local][batch] padded
    __shared__ short ch[32 * 33];       // h-chunk [unit_local][batch] padded
    const int b = blockIdx.x;
    const int tid = threadIdx.x;
    const int w = tid >> 6, l = tid & 63, lr = l & 15, lg = l >> 4;
    const int mt = w & 1, nt = w >> 1;
    const int r = nt * 16 + lr;                  // gate-local row 0..127
    const int gate = r >> 5, ul = r & 31;
    const int G = gate * 512 + b * 32 + ul;      // global gate row
    short8 bfg[16];
    const short* wrow = Whhb + (size_t)G * 512;
#pragma unroll
    for (int ks = 0; ks < 16; ++ks) bfg[ks] = *(const short8*)(wrow + ks * 32 + lg * 8);
    const int cu = tid >> 5, cb = tid & 31;
    float cr = c0[cb * 512 + b * 32 + cu];
    const int pb = tid >> 3;
    unsigned dmC = 0, dmP = 0;
#pragma unroll
    for (int q = 0; q < 16; ++q) {
        dmC |= (done[q * 32 + cb] ? 1u : 0u) << q;
        dmP |= (done[q * 32 + pb] ? 1u : 0u) << q;
    }
    float pr[4];
#pragma unroll
    for (int j = 0; j < 4; ++j)
        pr[j] = P[(size_t)(mt * 16 + lg * 4 + j) * 2048 + G];

    for (int t = 0; t < 16; ++t) {
        const u64* hin = (t & 1) ? hq1 : hq0;
        u64* hout      = (t & 1) ? hq0 : hq1;
        if (t > 0) {
            if (tid < 16) {
                while (__hip_atomic_load(flags + tid, __ATOMIC_RELAXED,
                                         __HIP_MEMORY_SCOPE_AGENT) < (unsigned)t)
                    __builtin_amdgcn_s_sleep(1);
            }
            __syncthreads();
        }
#pragma unroll
        for (int it = 0; it < 4; ++it) {
            int i = it * 1024 + tid;
            u64 g = __hip_atomic_load(hin + i, __ATOMIC_RELAXED, __HIP_MEMORY_SCOPE_AGENT);
            *(u64*)&hs[(i >> 7) * 520 + (i & 127) * 4] = g;
        }
        __syncthreads();
        f32x4 acc = {};
#pragma unroll
        for (int ks = 0; ks < 16; ++ks) {
            short8 a = *(const short8*)&hs[(mt * 16 + lr) * 520 + ks * 32 + lg * 8];
            acc = MFMA16(a, bfg[ks], acc);
        }
#pragma unroll
        for (int j = 0; j < 4; ++j)
            gb[gate * 1056 + ul * 33 + (mt * 16 + lg * 4 + j)] = acc[j] + pr[j];
        __syncthreads();
        {
            float gi = gb[0 * 1056 + cu * 33 + cb];
            float gf = gb[1 * 1056 + cu * 33 + cb];
            float gg = gb[2 * 1056 + cu * 33 + cb];
            float go = gb[3 * 1056 + cu * 33 + cb];
            float m = ((dmC >> t) & 1u) ? 0.f : 1.f;
            float ig = 1.f / (1.f + expf(-gi));
            float fg = 1.f / (1.f + expf(-gf));
            float gt = tanhf(gg);
            float og = 1.f / (1.f + expf(-go));
            float cn = fg * (cr * m) + ig * gt;
            float hn = og * tanhf(cn);
            cr = cn;
            ch[cu * 33 + cb] = f2bs(hn);
            if (t == 15) {
                outH[cb * 512 + b * 32 + cu] = hn;
                outC[cb * 512 + b * 32 + cu] = cn;
            }
        }
        __syncthreads();
        if (t < 15) {
            if (tid < 256) {
                int bb3 = tid >> 3, uq = (tid & 7) * 4;
                u64 q = 0;
                if (!((dmP >> (t + 1)) & 1u)) {
                    unsigned lo = ((unsigned)(unsigned short)ch[uq * 33 + bb3]) |
                                  (((unsigned)(unsigned short)ch[(uq + 1) * 33 + bb3]) << 16);
                    unsigned hi = ((unsigned)(unsigned short)ch[(uq + 2) * 33 + bb3]) |
                                  (((unsigned)(unsigned short)ch[(uq + 3) * 33 + bb3]) << 16);
                    q = (u64)lo | ((u64)hi << 32);
                }
                __hip_atomic_store(hout + bb3 * 128 + b * 8 + (tid & 7), q,
                                   __ATOMIC_RELAXED, __HIP_MEMORY_SCOPE_AGENT);
            }
            asm volatile("s_waitcnt vmcnt(0)" ::: "memory");
            __syncthreads();
            if (tid == 0)
                __hip_atomic_store(flags + b, (unsigned)(t + 1),
                                   __ATOMIC_RELAXED, __HIP_MEMORY_SCOPE_AGENT);
        }
        if (tid < 512) {
            int bb2 = tid >> 4, up = (tid & 15) * 2;
            unsigned pkv = ((unsigned)(unsigned short)ch[up * 33 + bb2]) |
                           (((unsigned)(unsigned short)ch[(up + 1) * 33 + bb2]) << 16);
            *(unsigned*)&nh[(size_t)(t * 32 + bb2) * 512 + b * 32 + up] = pkv;
        }
        int tp = (t < 15) ? t + 1 : 15;
#pragma unroll
        for (int j = 0; j < 4; ++j)
            pr[j] = P[(size_t)(tp * 32 + mt * 16 + lg * 4 + j) * 2048 + G];
    }
}

// ---------------- small heads: logits [512][8] + value [512] ----------------
__global__ void k_heads(const short* __restrict__ aAC,
                        const short* __restrict__ A2b, const float* __restrict__ Ab2,
                        const short* __restrict__ C2b, const float* __restrict__ Cb2,
                        float* __restrict__ out) {
    int idx = blockIdx.x * 4 + (threadIdx.x >> 6);
    int l = threadIdx.x & 63;
    if (idx >= 4608) return;
    int row = idx / 9, col = idx % 9;
    const short* act = aAC + (size_t)row * 1024 + (col < 8 ? 0 : 512);
    const short* wr  = (col < 8) ? (A2b + (size_t)col * 512) : C2b;
    short8 a = *(const short8*)(act + l * 8);
    short8 wv = *(const short8*)(wr + l * 8);
    float s = 0.f;
#pragma unroll
    for (int q = 0; q < 8; ++q) s += bs2f(a[q]) * bs2f(wv[q]);
#pragma unroll
    for (int off = 32; off > 0; off >>= 1) s += __shfl_xor(s, off, 64);
    if (l == 0) {
        if (col < 8) out[row * 8 + col] = s + Ab2[col];
        else out[4096 + row] = s + Cb2[0];
    }
}

// ---------------- launch ----------------

extern "C" void kernel_launch(void* const* d_in, const int* in_sizes, int n_in,
                              void* d_out, int out_size, void* d_ws, size_t ws_size,
                              hipStream_t stream) {
    (void)in_sizes; (void)n_in; (void)out_size; (void)ws_size;
    const float* x    = (const float*)d_in[0];
    const int*   done = (const int*)  d_in[1];
    const float* h0   = (const float*)d_in[2];
    const float* c0   = (const float*)d_in[3];
    const float* w1   = (const float*)d_in[4];
    const float* b1   = (const float*)d_in[5];
    const float* w2   = (const float*)d_in[6];
    const float* b2   = (const float*)d_in[7];
    const float* w3   = (const float*)d_in[8];
    const float* b3   = (const float*)d_in[9];
    const float* fcW  = (const float*)d_in[10];
    const float* fcb  = (const float*)d_in[11];
    const float* Wih  = (const float*)d_in[12];
    const float* Whh  = (const float*)d_in[13];
    const float* bih  = (const float*)d_in[14];
    const float* bhh  = (const float*)d_in[15];
    const float* A1   = (const float*)d_in[16];
    const float* Ab1  = (const float*)d_in[17];
    const float* A2   = (const float*)d_in[18];
    const float* Ab2  = (const float*)d_in[19];
    const float* C1   = (const float*)d_in[20];
    const float* Cb1  = (const float*)d_in[21];
    const float* C2   = (const float*)d_in[22];
    const float* Cb2  = (const float*)d_in[23];
    float* out = (float*)d_out;

    char* wsp = (char*)d_ws;
    auto alloc = [&](size_t bytes) {
        char* p = wsp; wsp += (bytes + 255) & ~(size_t)255; return p;
    };
    short* a3s  = (short*)alloc(5767168ull * 2);   // [512*176][64]
    short* hfc  = (short*)alloc(262144ull * 2);    // [512][512]
    float* P    = (float*)alloc(1048576ull * 4);   // [512][2048]
    short* whhb = (short*)alloc(1048576ull * 2);   // Whh bf16 [2048][512]
    u64*   hq0  = (u64*)  alloc(16384ull * 2);     // masked h, qword view
    u64*   hq1  = (u64*)  alloc(16384ull * 2);
    short* nh   = (short*)alloc(262144ull * 2);
    short* aAC  = (short*)alloc(524288ull * 2);    // [512][1024]
    float* part = (float*)alloc(2097152ull * 4);   // FC split-K 8 partials (8 MB)
    short* wc1  = (short*)alloc(6144ull * 2);
    short* wc2  = (short*)alloc(32768ull * 2);
    short* wc3  = (short*)alloc(36864ull * 2);
    short* fcwr = (short*)alloc(5767168ull * 2);
    short* wihb = (short*)alloc(1048576ull * 2);
    short* a1b  = (short*)alloc(262144ull * 2);
    short* c1b  = (short*)alloc(262144ull * 2);
    short* a2b  = (short*)alloc(4096ull * 2);
    short* c2b  = (short*)alloc(512ull * 2);
    float* bias2  = (float*)alloc(2048ull * 4);
    float* biasAC = (float*)alloc(1024ull * 4);
    unsigned* flags = (unsigned*)alloc(256);

    // all prep in one launch
    k_megaprep<<<3432, 256, 0, stream>>>(w1, w2, w3, fcW, Wih, Whh, A1, C1, A2, C2,
                                         h0, done, bih, bhh, Ab1, Cb1,
                                         wc1, wc2, wc3, fcwr, wihb, whhb,
                                         a1b, c1b, a2b, c2b, (short*)hq0,
                                         bias2, biasAC, flags);

    // fused conv1+conv2+conv3 (a1, a2 never leave LDS), 512 threads, min-occ 2 waves/EU
    k_conv123<<<512, 512, 0, stream>>>(x, wc1, b1, wc2, b2, wc3, b3, a3s);

    // FC: split-K 8 + epilogue
    k_gemm_mfma<<<dim3(8, 8, 8), 256, 0, stream>>>(a3s, fcwr, part, 512, 512, 11264, 1408);
    k_epilogue<<<256, 256, 0, stream>>>(part, fcb, hfc, nullptr, 262144, 512, 8, 0.2f);

    // P = hfc @ Wih^T + (bih + bhh)  (fused epilogue, f32 out)
    k_gemm_bias<<<dim3(32, 8), 256, 0, stream>>>(hfc, wihb, bias2, nullptr, P,
                                                 512, 2048, 512, 1.0f);

    // LSTM: one persistent launch (v4, best known)
    k_lstm_all4<<<16, 1024, 0, stream>>>(P, whhb, done, hq0, hq1, c0, nh,
                                         out + 4608, out + 20992, flags);

    // heads: combined [A1;C1] GEMM (fused epilogue, bf16 out)
    k_gemm_bias<<<dim3(16, 8), 256, 0, stream>>>(nh, a1b, biasAC, aAC, nullptr,
                                                 512, 1024, 512, 0.01f);
    k_heads<<<1152, 256, 0, stream>>>(aAC, a2b, Ab2, c2b, Cb2, out);
}

// Round 17
// 194.239 us; speedup vs baseline: 1.0677x; 1.0354x over previous
//
#include <hip/hip_runtime.h>
#include <hip/hip_bf16.h>
#include <math.h>

using short8 = __attribute__((ext_vector_type(8))) short;   // 8 bf16 (4 VGPR)
using f32x4  = __attribute__((ext_vector_type(4))) float;   // MFMA acc
typedef unsigned long long u64;

#define MFMA16(a, b, c) __builtin_amdgcn_mfma_f32_16x16x32_bf16(a, b, c, 0, 0, 0)

__device__ __forceinline__ short f2bs(float f) {
    __hip_bfloat16 h = __float2bfloat16(f);          // RNE
    return __builtin_bit_cast(short, h);
}
__device__ __forceinline__ float bs2f(short s) {
    return __uint_as_float(((unsigned)(unsigned short)s) << 16);
}

// ---------------- mega-prep: all weight conversions + transposes in ONE launch ----------------
__global__ void __launch_bounds__(256) k_megaprep(
        const float* __restrict__ w1, const float* __restrict__ w2,
        const float* __restrict__ w3, const float* __restrict__ fcW,
        const float* __restrict__ Wih, const float* __restrict__ Whh,
        const float* __restrict__ A1, const float* __restrict__ C1,
        const float* __restrict__ A2, const float* __restrict__ C2,
        const float* __restrict__ h0, const int* __restrict__ done,
        const float* __restrict__ bih, const float* __restrict__ bhh,
        const float* __restrict__ Ab1, const float* __restrict__ Cb1,
        short* __restrict__ wc1, short* __restrict__ wc2, short* __restrict__ wc3,
        short* __restrict__ fcwr, short* __restrict__ wihb, short* __restrict__ whhb,
        short* __restrict__ a1b, short* __restrict__ c1b, short* __restrict__ a2b,
        short* __restrict__ c2b, short* __restrict__ hm0,
        float* __restrict__ bias2, float* __restrict__ biasAC, unsigned* __restrict__ flags) {
    __shared__ short t[176 * 76];
    const int bid = blockIdx.x, tid = threadIdx.x;

    auto cvt4 = [&](const float* in, short* out, int i) {
        float4 v = *(const float4*)(in + i * 4);
        out[i * 4 + 0] = f2bs(v.x); out[i * 4 + 1] = f2bs(v.y);
        out[i * 4 + 2] = f2bs(v.z); out[i * 4 + 3] = f2bs(v.w);
    };

    if (bid < 512) {
        // fcW [512][11264] (K = oc*176+pix) -> fcwr [512][pix*64+oc]
        int r = bid;
        for (int it = 0; it < 11; ++it) {
            int c4 = it * 256 + tid;
            float4 v = *(const float4*)(fcW + (size_t)r * 11264 + c4 * 4);
            int c = c4 * 4;
            int oc = c / 176, pix = c % 176;
            t[(pix + 0) * 76 + oc] = f2bs(v.x);
            t[(pix + 1) * 76 + oc] = f2bs(v.y);
            t[(pix + 2) * 76 + oc] = f2bs(v.z);
            t[(pix + 3) * 76 + oc] = f2bs(v.w);
        }
        __syncthreads();
        for (int it = 0; it < 6; ++it) {
            int j8 = it * 256 + tid;
            if (j8 < 1408) {
                int j = j8 * 8, pix = j >> 6, oc0 = j & 63;
                const short* tp = &t[pix * 76 + oc0];
                short8 v;
                ((uint2*)&v)[0] = *(const uint2*)tp;
                ((uint2*)&v)[1] = *(const uint2*)(tp + 4);
                *(short8*)&fcwr[(size_t)r * 11264 + j] = v;
            }
        }
    } else if (bid < 1536) {
        cvt4(Wih, wihb, (bid - 512) * 256 + tid);
    } else if (bid < 2560) {
        cvt4(Whh, whhb, (bid - 1536) * 256 + tid);
    } else if (bid < 2816) {
        cvt4(A1, a1b, (bid - 2560) * 256 + tid);
    } else if (bid < 3072) {
        cvt4(C1, c1b, (bid - 2816) * 256 + tid);
    } else if (bid < 3078) {
        cvt4(w1, wc1, (bid - 3072) * 256 + tid);       // layout already (ic*64+kh*8+kw)
    } else if (bid < 3206) {
        int i = (bid - 3078) * 256 + tid;              // 32768
        int oc = i >> 9, col = i & 511;
        int kh = col >> 7, kw = (col >> 5) & 3, ic = col & 31;
        wc2[i] = f2bs(w2[((oc * 32 + ic) * 4 + kh) * 4 + kw]);
    } else if (bid < 3350) {
        int i = (bid - 3206) * 256 + tid;              // 36864
        int oc = i / 576, col = i % 576;
        int kh = col / 192, r = col % 192, kw = r >> 6, ic = r & 63;
        wc3[i] = f2bs(w3[((oc * 64 + ic) * 3 + kh) * 3 + kw]);
    } else if (bid < 3354) {
        cvt4(A2, a2b, (bid - 3350) * 256 + tid);
    } else if (bid < 3355) {
        if (tid < 128) cvt4(C2, c2b, tid);
    } else if (bid < 3419) {
        int i = (bid - 3355) * 256 + tid;              // 16384
        float m = 1.f - (float)done[i >> 9];
        hm0[i] = f2bs(h0[i] * m);
    } else if (bid < 3427) {
        int i = (bid - 3419) * 256 + tid;              // 2048
        bias2[i] = bih[i] + bhh[i];
    } else if (bid < 3431) {
        int i = (bid - 3427) * 256 + tid;              // 1024
        biasAC[i] = (i < 512) ? Ab1[i] : Cb1[i - 512];
    } else {
        if (tid < 16) flags[tid] = 0u;
    }
}

// ---------------- fused conv1+conv2+conv3: x image -> a3 image (round-13 best: 87 µs) ----------------
// a1 lives only in LDS (img1, swizzled); a2 only in LDS (img2). 1 block/CU (106 KB LDS).
__global__ void __launch_bounds__(256) k_conv123(
        const float* __restrict__ x,   const short* __restrict__ Wc1,
        const float* __restrict__ b1,
        const short* __restrict__ Wc2, const float* __restrict__ b2,
        const short* __restrict__ Wc3, const float* __restrict__ b3,
        short* __restrict__ y3) {
    __shared__ short img1[36192];       // [1131 px][32 oc] swizzled (conv1 out / conv2 in)
    __shared__ short img2[14976];       // [13][18][64] swizzled (conv2 out / conv3 in)
    __shared__ short ct[2048];          // conv1: [wave][16px][32oc]; conv2/3: [par][16px][64oc]
    const int n = blockIdx.x, tid = threadIdx.x;
    const int w = tid >> 6, l = tid & 63, lr = l & 15, lg = l >> 4;
    const int par = w >> 1, nfh = w & 1;

    // ---- conv1 phase: x[n] (f32, HBM/L3) -> img1 (bf16 LDS, swizzled a1 layout) ----
    {
        short8 bf[6][2];
#pragma unroll
        for (int ks = 0; ks < 6; ++ks)
#pragma unroll
            for (int nf = 0; nf < 2; ++nf)
                bf[ks][nf] = *(const short8*)&Wc1[(nf * 16 + lr) * 192 + ks * 32 + lg * 8];
        const float bc0 = b1[lr], bc1 = b1[16 + lr];
        const float* xb = x + (size_t)n * 57600;
        auto tileBase = [&](int tt) -> const float* {
            int p = tt * 16 + lr; if (p > 1130) p = 1130;
            int oh = p / 39, ow = p - oh * 39;
            return xb + (oh * 4) * 160 + ow * 4;
        };
        const int ntiles = (w == 3) ? 17 : 18;           // tiles tt = w + 4i, 71 total
        float4 fA[6][2], fB[6][2];
        {
            const float* base = tileBase(w);
#pragma unroll
            for (int ks = 0; ks < 6; ++ks) {
                int ic = ks >> 1, kh = (ks & 1) * 4 + lg;
                const float* ap = base + ic * 19200 + kh * 160;
                fA[ks][0] = *(const float4*)ap;
                fA[ks][1] = *(const float4*)(ap + 4);
            }
        }
        for (int i = 0; i < ntiles; ++i) {
            const int tt = i * 4 + w;
            if (i + 1 < ntiles) {                        // prefetch next tile
                const float* nb = tileBase(tt + 4);
#pragma unroll
                for (int ks = 0; ks < 6; ++ks) {
                    int ic = ks >> 1, kh = (ks & 1) * 4 + lg;
                    const float* ap = nb + ic * 19200 + kh * 160;
                    fB[ks][0] = *(const float4*)ap;
                    fB[ks][1] = *(const float4*)(ap + 4);
                }
            }
            f32x4 acc[2] = {};
#pragma unroll
            for (int ks = 0; ks < 6; ++ks) {
                short8 a;
                a[0] = f2bs(fA[ks][0].x); a[1] = f2bs(fA[ks][0].y);
                a[2] = f2bs(fA[ks][0].z); a[3] = f2bs(fA[ks][0].w);
                a[4] = f2bs(fA[ks][1].x); a[5] = f2bs(fA[ks][1].y);
                a[6] = f2bs(fA[ks][1].z); a[7] = f2bs(fA[ks][1].w);
                acc[0] = MFMA16(a, bf[ks][0], acc[0]);
                acc[1] = MFMA16(a, bf[ks][1], acc[1]);
            }
#pragma unroll
            for (int j = 0; j < 4; ++j) {
                ct[w * 512 + (lg * 4 + j) * 32 + lr] = f2bs(fmaxf(acc[0][j] + bc0, 0.f));
                ct[w * 512 + (lg * 4 + j) * 32 + 16 + lr] = f2bs(fmaxf(acc[1][j] + bc1, 0.f));
            }
            asm volatile("s_waitcnt lgkmcnt(0)" ::: "memory");
            {
                int row = l >> 2, c8 = (l & 3) * 8;
                int pg = tt * 16 + row;
                if (pg < 1131) {
                    short8 v = *(const short8*)&ct[w * 512 + row * 32 + c8];
                    int b = pg * 64 + c8 * 2;            // linear byte offset in a1 layout
                    b ^= ((b >> 7) & 7) << 4;            // img1 swizzle (matches conv2 reads)
                    *(short8*)((char*)img1 + b) = v;
                }
            }
            asm volatile("s_waitcnt lgkmcnt(0)" ::: "memory");
            if (i + 1 < ntiles) {
#pragma unroll
                for (int ks = 0; ks < 6; ++ks) {
                    fA[ks][0] = fB[ks][0];
                    fA[ks][1] = fB[ks][1];
                }
            }
        }
    }
    __syncthreads();

    // ---- conv2 phase: img1 -> img2 ----
    {
        short8 bfg[16][2];
#pragma unroll
        for (int ks = 0; ks < 16; ++ks)
#pragma unroll
            for (int q2 = 0; q2 < 2; ++q2)
                bfg[ks][q2] = *(const short8*)&Wc2[(nfh * 32 + q2 * 16 + lr) * 512 + ks * 32 + lg * 8];
        float bc[2] = {b2[nfh * 32 + lr], b2[nfh * 32 + 16 + lr]};
        for (int t = par; t < 16; t += 2) {
            int p = t * 16 + lr;
            int pc = p < 234 ? p : 233;
            int oh = pc / 18, ow = pc - oh * 18;
            int base = (oh * 2 * 39 + ow * 2) * 64 + lg * 16;
            f32x4 acc[2] = {};
#pragma unroll
            for (int ks = 0; ks < 16; ++ks) {
                int kh = ks >> 2, kw = ks & 3;
                int b = base + (kh * 39 + kw) * 64;
                b ^= ((b >> 7) & 7) << 4;
                short8 a = *(const short8*)((const char*)img1 + b);
                acc[0] = MFMA16(a, bfg[ks][0], acc[0]);
                acc[1] = MFMA16(a, bfg[ks][1], acc[1]);
            }
#pragma unroll
            for (int q2 = 0; q2 < 2; ++q2)
#pragma unroll
                for (int j = 0; j < 4; ++j)
                    ct[par * 1024 + (lg * 4 + j) * 64 + nfh * 32 + q2 * 16 + lr] =
                        f2bs(fmaxf(acc[q2][j] + bc[q2], 0.f));
            __syncthreads();
            int li = nfh * 64 + l;
            int row = li >> 3, c8 = (li & 7) * 8;
            short8 v = *(const short8*)&ct[par * 1024 + row * 64 + c8];
            int pg = t * 16 + row;
            if (pg < 234) {
                int b = (pg * 64 + c8) * 2;              // byte offset in img2
                b ^= ((b >> 7) & 7) << 4;
                *(short8*)((char*)img2 + b) = v;
            }
            __syncthreads();
        }
    }
    __syncthreads();

    // ---- conv3 phase: img2 -> a3 (global) ----
    {
        short8 bfg[18][2];
#pragma unroll
        for (int ks = 0; ks < 18; ++ks)
#pragma unroll
            for (int q2 = 0; q2 < 2; ++q2)
                bfg[ks][q2] = *(const short8*)&Wc3[(nfh * 32 + q2 * 16 + lr) * 576 + ks * 32 + lg * 8];
        float bc[2] = {b3[nfh * 32 + lr], b3[nfh * 32 + 16 + lr]};
        for (int t = par; t < 12; t += 2) {
            int p = t * 16 + lr;
            int pc = p < 176 ? p : 175;
            int oh = pc >> 4, ow = pc & 15;
            int base = (oh * 18 + ow) * 128 + lg * 16;
            f32x4 acc[2] = {};
#pragma unroll
            for (int ks = 0; ks < 18; ++ks) {
                int kh = ks / 6, r6 = ks % 6, kw = r6 >> 1, ich = r6 & 1;
                int b = base + (kh * 18 + kw) * 128 + ich * 64;
                b ^= ((b >> 7) & 7) << 4;
                short8 a = *(const short8*)((const char*)img2 + b);
                acc[0] = MFMA16(a, bfg[ks][0], acc[0]);
                acc[1] = MFMA16(a, bfg[ks][1], acc[1]);
            }
#pragma unroll
            for (int q2 = 0; q2 < 2; ++q2)
#pragma unroll
                for (int j = 0; j < 4; ++j)
                    ct[par * 1024 + (lg * 4 + j) * 64 + nfh * 32 + q2 * 16 + lr] =
                        f2bs(fmaxf(acc[q2][j] + bc[q2], 0.f));
            __syncthreads();
            int li = nfh * 64 + l;
            int row = li >> 3, c8 = (li & 7) * 8;
            short8 v = *(const short8*)&ct[par * 1024 + row * 64 + c8];
            int pg = t * 16 + row;
            if (pg < 176)
                *(short8*)&y3[((size_t)n * 176 + pg) * 64 + c8] = v;
            __syncthreads();
        }
    }
}

// ---------------- MFMA GEMM core (BK=64): part[z][M][N] = A @ W^T ----------------
__global__ void k_gemm_mfma(const short* __restrict__ A, const short* __restrict__ W,
                            float* __restrict__ part, int M, int N, int K, int kPerSplit) {
    __shared__ short As[2][64 * 40];
    __shared__ short Ws[2][64 * 40];
    const int tid = threadIdx.x;
    const int m0 = blockIdx.y * 64, n0 = blockIdx.x * 64;
    const int k0s = blockIdx.z * kPerSplit, k0e = k0s + kPerSplit;
    const int w = tid >> 6, l = tid & 63;
    const int wr = w >> 1, wc = w & 1;
    const int sr = tid >> 2, sc = tid & 3;
    const int lr = l & 15, lg = l >> 4;
    f32x4 acc[2][2] = {};
    for (int k0 = k0s; k0 < k0e; k0 += 64) {
        short8 av0 = *(const short8*)(A + (size_t)(m0 + sr) * K + k0 + sc * 8);
        short8 av1 = *(const short8*)(A + (size_t)(m0 + sr) * K + k0 + 32 + sc * 8);
        short8 wv0 = *(const short8*)(W + (size_t)(n0 + sr) * K + k0 + sc * 8);
        short8 wv1 = *(const short8*)(W + (size_t)(n0 + sr) * K + k0 + 32 + sc * 8);
        __syncthreads();
        *(short8*)&As[0][sr * 40 + sc * 8] = av0;
        *(short8*)&As[1][sr * 40 + sc * 8] = av1;
        *(short8*)&Ws[0][sr * 40 + sc * 8] = wv0;
        *(short8*)&Ws[1][sr * 40 + sc * 8] = wv1;
        __syncthreads();
        int cb = lg * 8;
#pragma unroll
        for (int h = 0; h < 2; ++h) {
            short8 a0 = *(const short8*)&As[h][(wr * 32 + lr) * 40 + cb];
            short8 a1 = *(const short8*)&As[h][(wr * 32 + 16 + lr) * 40 + cb];
            short8 b0 = *(const short8*)&Ws[h][(wc * 32 + lr) * 40 + cb];
            short8 b1 = *(const short8*)&Ws[h][(wc * 32 + 16 + lr) * 40 + cb];
            acc[0][0] = MFMA16(a0, b0, acc[0][0]);
            acc[0][1] = MFMA16(a0, b1, acc[0][1]);
            acc[1][0] = MFMA16(a1, b0, acc[1][0]);
            acc[1][1] = MFMA16(a1, b1, acc[1][1]);
        }
    }
    float* pp = part + (size_t)blockIdx.z * M * N;
#pragma unroll
    for (int mi = 0; mi < 2; ++mi)
#pragma unroll
        for (int ni = 0; ni < 2; ++ni)
#pragma unroll
            for (int j = 0; j < 4; ++j) {
                int row = m0 + wr * 32 + mi * 16 + lg * 4 + j;
                int col = n0 + wc * 32 + ni * 16 + lr;
                pp[(size_t)row * N + col] = acc[mi][ni][j];
            }
}

// FC epilogue: sum splits + bias + leaky -> bf16/f32
__global__ void k_epilogue(const float* __restrict__ part, const float* __restrict__ bias,
                           short* __restrict__ out_b, float* __restrict__ out_f,
                           int MN, int N, int S, float slope) {
    int i = (blockIdx.x * 256 + threadIdx.x) * 4;
    if (i >= MN) return;
    float4 v = *(const float4*)(part + i);
    for (int s = 1; s < S; ++s) {
        float4 p = *(const float4*)(part + (size_t)s * MN + i);
        v.x += p.x; v.y += p.y; v.z += p.z; v.w += p.w;
    }
    float4 b = *(const float4*)(bias + (i % N));
    v.x += b.x; v.y += b.y; v.z += b.z; v.w += b.w;
    v.x = (v.x >= 0.f) ? v.x : v.x * slope;
    v.y = (v.y >= 0.f) ? v.y : v.y * slope;
    v.z = (v.z >= 0.f) ? v.z : v.z * slope;
    v.w = (v.w >= 0.f) ? v.w : v.w * slope;
    if (out_b) {
        out_b[i + 0] = f2bs(v.x); out_b[i + 1] = f2bs(v.y);
        out_b[i + 2] = f2bs(v.z); out_b[i + 3] = f2bs(v.w);
    }
    if (out_f) *(float4*)(out_f + i) = v;
}

// ---------------- GEMM with fused bias+leaky epilogue (BK=64) ----------------
__global__ void k_gemm_bias(const short* __restrict__ A, const short* __restrict__ W,
                            const float* __restrict__ bias, short* __restrict__ out_b,
                            float* __restrict__ out_f, int M, int N, int K, float slope) {
    __shared__ short As[2][64 * 40];
    __shared__ short Ws[2][64 * 40];
    const int tid = threadIdx.x;
    const int m0 = blockIdx.y * 64, n0 = blockIdx.x * 64;
    const int w = tid >> 6, l = tid & 63;
    const int wr = w >> 1, wc = w & 1;
    const int sr = tid >> 2, sc = tid & 3;
    const int lr = l & 15, lg = l >> 4;
    f32x4 acc[2][2] = {};
    for (int k0 = 0; k0 < K; k0 += 64) {
        short8 av0 = *(const short8*)(A + (size_t)(m0 + sr) * K + k0 + sc * 8);
        short8 av1 = *(const short8*)(A + (size_t)(m0 + sr) * K + k0 + 32 + sc * 8);
        short8 wv0 = *(const short8*)(W + (size_t)(n0 + sr) * K + k0 + sc * 8);
        short8 wv1 = *(const short8*)(W + (size_t)(n0 + sr) * K + k0 + 32 + sc * 8);
        __syncthreads();
        *(short8*)&As[0][sr * 40 + sc * 8] = av0;
        *(short8*)&As[1][sr * 40 + sc * 8] = av1;
        *(short8*)&Ws[0][sr * 40 + sc * 8] = wv0;
        *(short8*)&Ws[1][sr * 40 + sc * 8] = wv1;
        __syncthreads();
        int cb = lg * 8;
#pragma unroll
        for (int h = 0; h < 2; ++h) {
            short8 a0 = *(const short8*)&As[h][(wr * 32 + lr) * 40 + cb];
            short8 a1 = *(const short8*)&As[h][(wr * 32 + 16 + lr) * 40 + cb];
            short8 b0 = *(const short8*)&Ws[h][(wc * 32 + lr) * 40 + cb];
            short8 b1 = *(const short8*)&Ws[h][(wc * 32 + 16 + lr) * 40 + cb];
            acc[0][0] = MFMA16(a0, b0, acc[0][0]);
            acc[0][1] = MFMA16(a0, b1, acc[0][1]);
            acc[1][0] = MFMA16(a1, b0, acc[1][0]);
            acc[1][1] = MFMA16(a1, b1, acc[1][1]);
        }
    }
#pragma unroll
    for (int mi = 0; mi < 2; ++mi)
#pragma unroll
        for (int ni = 0; ni < 2; ++ni)
#pragma unroll
            for (int j = 0; j < 4; ++j) {
                int row = m0 + wr * 32 + mi * 16 + lg * 4 + j;
                int col = n0 + wc * 32 + ni * 16 + lr;
                float v = acc[mi][ni][j] + bias[col];
                v = (v >= 0.f) ? v : v * slope;
                if (out_f) out_f[(size_t)row * N + col] = v;
                else       out_b[(size_t)row * N + col] = f2bs(v);
            }
}

// ---------------- persistent LSTM v4 (best known: 82 µs — structural floor) ----------------
__global__ void __launch_bounds__(1024) k_lstm_all4(
        const float* __restrict__ P, const short* __restrict__ Whhb,
        const int* __restrict__ done, u64* __restrict__ hq0, u64* __restrict__ hq1,
        const float* __restrict__ c0, short* __restrict__ nh,
        float* __restrict__ outH, float* __restrict__ outC, unsigned* __restrict__ flags) {
    __shared__ short hs[32 * 520];      // h staging [32 batch][512+8]
    __shared__ float gb[4 * 32 * 33];   // gates [gate][unit_local][batch] padded
    __shared__ short ch[32 * 33];       // h-chunk [unit_local][batch] padded
    const int b = blockIdx.x;
    const int tid = threadIdx.x;
    const int w = tid >> 6, l = tid & 63, lr = l & 15, lg = l >> 4;
    const int mt = w & 1, nt = w >> 1;
    const int r = nt * 16 + lr;                  // gate-local row 0..127
    const int gate = r >> 5, ul = r & 31;
    const int G = gate * 512 + b * 32 + ul;      // global gate row
    short8 bfg[16];
    const short* wrow = Whhb + (size_t)G * 512;
#pragma unroll
    for (int ks = 0; ks < 16; ++ks) bfg[ks] = *(const short8*)(wrow + ks * 32 + lg * 8);
    const int cu = tid >> 5, cb = tid & 31;
    float cr = c0[cb * 512 + b * 32 + cu];
    const int pb = tid >> 3;
    unsigned dmC = 0, dmP = 0;
#pragma unroll
    for (int q = 0; q < 16; ++q) {
        dmC |= (done[q * 32 + cb] ? 1u : 0u) << q;
        dmP |= (done[q * 32 + pb] ? 1u : 0u) << q;
    }
    float pr[4];
#pragma unroll
    for (int j = 0; j < 4; ++j)
        pr[j] = P[(size_t)(mt * 16 + lg * 4 + j) * 2048 + G];

    for (int t = 0; t < 16; ++t) {
        const u64* hin = (t & 1) ? hq1 : hq0;
        u64* hout      = (t & 1) ? hq0 : hq1;
        if (t > 0) {
            if (tid < 16) {
                while (__hip_atomic_load(flags + tid, __ATOMIC_RELAXED,
                                         __HIP_MEMORY_SCOPE_AGENT) < (unsigned)t)
                    __builtin_amdgcn_s_sleep(1);
            }
            __syncthreads();
        }
#pragma unroll
        for (int it = 0; it < 4; ++it) {
            int i = it * 1024 + tid;
            u64 g = __hip_atomic_load(hin + i, __ATOMIC_RELAXED, __HIP_MEMORY_SCOPE_AGENT);
            *(u64*)&hs[(i >> 7) * 520 + (i & 127) * 4] = g;
        }
        __syncthreads();
        f32x4 acc = {};
#pragma unroll
        for (int ks = 0; ks < 16; ++ks) {
            short8 a = *(const short8*)&hs[(mt * 16 + lr) * 520 + ks * 32 + lg * 8];
            acc = MFMA16(a, bfg[ks], acc);
        }
#pragma unroll
        for (int j = 0; j < 4; ++j)
            gb[gate * 1056 + ul * 33 + (mt * 16 + lg * 4 + j)] = acc[j] + pr[j];
        __syncthreads();
        {
            float gi = gb[0 * 1056 + cu * 33 + cb];
            float gf = gb[1 * 1056 + cu * 33 + cb];
            float gg = gb[2 * 1056 + cu * 33 + cb];
            float go = gb[3 * 1056 + cu * 33 + cb];
            float m = ((dmC >> t) & 1u) ? 0.f : 1.f;
            float ig = 1.f / (1.f + expf(-gi));
            float fg = 1.f / (1.f + expf(-gf));
            float gt = tanhf(gg);
            float og = 1.f / (1.f + expf(-go));
            float cn = fg * (cr * m) + ig * gt;
            float hn = og * tanhf(cn);
            cr = cn;
            ch[cu * 33 + cb] = f2bs(hn);
            if (t == 15) {
                outH[cb * 512 + b * 32 + cu] = hn;
                outC[cb * 512 + b * 32 + cu] = cn;
            }
        }
        __syncthreads();
        if (t < 15) {
            if (tid < 256) {
                int bb3 = tid >> 3, uq = (tid & 7) * 4;
                u64 q = 0;
                if (!((dmP >> (t + 1)) & 1u)) {
                    unsigned lo = ((unsigned)(unsigned short)ch[uq * 33 + bb3]) |
                                  (((unsigned)(unsigned short)ch[(uq + 1) * 33 + bb3]) << 16);
                    unsigned hi = ((unsigned)(unsigned short)ch[(uq + 2) * 33 + bb3]) |
                                  (((unsigned)(unsigned short)ch[(uq + 3) * 33 + bb3]) << 16);
                    q = (u64)lo | ((u64)hi << 32);
                }
                __hip_atomic_store(hout + bb3 * 128 + b * 8 + (tid & 7), q,
                                   __ATOMIC_RELAXED, __HIP_MEMORY_SCOPE_AGENT);
            }
            asm volatile("s_waitcnt vmcnt(0)" ::: "memory");
            __syncthreads();
            if (tid == 0)
                __hip_atomic_store(flags + b, (unsigned)(t + 1),
                                   __ATOMIC_RELAXED, __HIP_MEMORY_SCOPE_AGENT);
        }
        if (tid < 512) {
            int bb2 = tid >> 4, up = (tid & 15) * 2;
            unsigned pkv = ((unsigned)(unsigned short)ch[up * 33 + bb2]) |
                           (((unsigned)(unsigned short)ch[(up + 1) * 33 + bb2]) << 16);
            *(unsigned*)&nh[(size_t)(t * 32 + bb2) * 512 + b * 32 + up] = pkv;
        }
        int tp = (t < 15) ? t + 1 : 15;
#pragma unroll
        for (int j = 0; j < 4; ++j)
            pr[j] = P[(size_t)(tp * 32 + mt * 16 + lg * 4 + j) * 2048 + G];
    }
}

// ---------------- small heads: logits [512][8] + value [512] ----------------
__global__ void k_heads(const short* __restrict__ aAC,
                        const short* __restrict__ A2b, const float* __restrict__ Ab2,
                        const short* __restrict__ C2b, const float* __restrict__ Cb2,
                        float* __restrict__ out) {
    int idx = blockIdx.x * 4 + (threadIdx.x >> 6);
    int l = threadIdx.x & 63;
    if (idx >= 4608) return;
    int row = idx / 9, col = idx % 9;
    const short* act = aAC + (size_t)row * 1024 + (col < 8 ? 0 : 512);
    const short* wr  = (col < 8) ? (A2b + (size_t)col * 512) : C2b;
    short8 a = *(const short8*)(act + l * 8);
    short8 wv = *(const short8*)(wr + l * 8);
    float s = 0.f;
#pragma unroll
    for (int q = 0; q < 8; ++q) s += bs2f(a[q]) * bs2f(wv[q]);
#pragma unroll
    for (int off = 32; off > 0; off >>= 1) s += __shfl_xor(s, off, 64);
    if (l == 0) {
        if (col < 8) out[row * 8 + col] = s + Ab2[col];
        else out[4096 + row] = s + Cb2[0];
    }
}

// ---------------- launch ----------------

extern "C" void kernel_launch(void* const* d_in, const int* in_sizes, int n_in,
                              void* d_out, int out_size, void* d_ws, size_t ws_size,
                              hipStream_t stream) {
    (void)in_sizes; (void)n_in; (void)out_size; (void)ws_size;
    const float* x    = (const float*)d_in[0];
    const int*   done = (const int*)  d_in[1];
    const float* h0   = (const float*)d_in[2];
    const float* c0   = (const float*)d_in[3];
    const float* w1   = (const float*)d_in[4];
    const float* b1   = (const float*)d_in[5];
    const float* w2   = (const float*)d_in[6];
    const float* b2   = (const float*)d_in[7];
    const float* w3   = (const float*)d_in[8];
    const float* b3   = (const float*)d_in[9];
    const float* fcW  = (const float*)d_in[10];
    const float* fcb  = (const float*)d_in[11];
    const float* Wih  = (const float*)d_in[12];
    const float* Whh  = (const float*)d_in[13];
    const float* bih  = (const float*)d_in[14];
    const float* bhh  = (const float*)d_in[15];
    const float* A1   = (const float*)d_in[16];
    const float* Ab1  = (const float*)d_in[17];
    const float* A2   = (const float*)d_in[18];
    const float* Ab2  = (const float*)d_in[19];
    const float* C1   = (const float*)d_in[20];
    const float* Cb1  = (const float*)d_in[21];
    const float* C2   = (const float*)d_in[22];
    const float* Cb2  = (const float*)d_in[23];
    float* out = (float*)d_out;

    char* wsp = (char*)d_ws;
    auto alloc = [&](size_t bytes) {
        char* p = wsp; wsp += (bytes + 255) & ~(size_t)255; return p;
    };
    short* a3s  = (short*)alloc(5767168ull * 2);   // [512*176][64]
    short* hfc  = (short*)alloc(262144ull * 2);    // [512][512]
    float* P    = (float*)alloc(1048576ull * 4);   // [512][2048]
    short* whhb = (short*)alloc(1048576ull * 2);   // Whh bf16 [2048][512]
    u64*   hq0  = (u64*)  alloc(16384ull * 2);     // masked h, qword view
    u64*   hq1  = (u64*)  alloc(16384ull * 2);
    short* nh   = (short*)alloc(262144ull * 2);
    short* aAC  = (short*)alloc(524288ull * 2);    // [512][1024]
    float* part = (float*)alloc(2097152ull * 4);   // FC split-K 8 partials (8 MB)
    short* wc1  = (short*)alloc(6144ull * 2);
    short* wc2  = (short*)alloc(32768ull * 2);
    short* wc3  = (short*)alloc(36864ull * 2);
    short* fcwr = (short*)alloc(5767168ull * 2);
    short* wihb = (short*)alloc(1048576ull * 2);
    short* a1b  = (short*)alloc(262144ull * 2);
    short* c1b  = (short*)alloc(262144ull * 2);
    short* a2b  = (short*)alloc(4096ull * 2);
    short* c2b  = (short*)alloc(512ull * 2);
    float* bias2  = (float*)alloc(2048ull * 4);
    float* biasAC = (float*)alloc(1024ull * 4);
    unsigned* flags = (unsigned*)alloc(256);

    // all prep in one launch
    k_megaprep<<<3432, 256, 0, stream>>>(w1, w2, w3, fcW, Wih, Whh, A1, C1, A2, C2,
                                         h0, done, bih, bhh, Ab1, Cb1,
                                         wc1, wc2, wc3, fcwr, wihb, whhb,
                                         a1b, c1b, a2b, c2b, (short*)hq0,
                                         bias2, biasAC, flags);

    // fused conv1+conv2+conv3 (a1, a2 never leave LDS), round-13 best config
    k_conv123<<<512, 256, 0, stream>>>(x, wc1, b1, wc2, b2, wc3, b3, a3s);

    // FC: split-K 8 + epilogue
    k_gemm_mfma<<<dim3(8, 8, 8), 256, 0, stream>>>(a3s, fcwr, part, 512, 512, 11264, 1408);
    k_epilogue<<<256, 256, 0, stream>>>(part, fcb, hfc, nullptr, 262144, 512, 8, 0.2f);

    // P = hfc @ Wih^T + (bih + bhh)  (fused epilogue, f32 out)
    k_gemm_bias<<<dim3(32, 8), 256, 0, stream>>>(hfc, wihb, bias2, nullptr, P,
                                                 512, 2048, 512, 1.0f);

    // LSTM: one persistent launch (v4, best known)
    k_lstm_all4<<<16, 1024, 0, stream>>>(P, whhb, done, hq0, hq1, c0, nh,
                                         out + 4608, out + 20992, flags);

    // heads: combined [A1;C1] GEMM (fused epilogue, bf16 out)
    k_gemm_bias<<<dim3(16, 8), 256, 0, stream>>>(nh, a1b, biasAC, aAC, nullptr,
                                                 512, 1024, 512, 0.01f);
    k_heads<<<1152, 256, 0, stream>>>(aAC, a2b, Ab2, c2b, Cb2, out);
}